// Round 2
// baseline (10584.320 us; speedup 1.0000x reference)
//
#include <hip/hip_runtime.h>

// HeteroGNN: 2-layer bipartite single-head GAT (users<->badges).
// Strategy: per-node dense kernels + per-edge atomic passes.
//   - alpha_d folded: alpha_d = x_dst @ (Wd @ a_d)   (hd never materialized)
//   - softmax max-subtraction dropped (mathematically identical, no overflow)
//   - per-edge e/w recomputed from L2-resident alpha tables (no 20MB spill)

#define NEG_SLOPE 0.2f

__device__ __forceinline__ float lrelu(float x) { return x > 0.f ? x : NEG_SLOPE * x; }

// v[f] = sum_c W[f*C+c] * a[c]   (W is F x C row-major). Launch F threads.
__global__ void k_wa(const float* __restrict__ W, const float* __restrict__ a,
                     float* __restrict__ v, int F, int C) {
  int f = blockIdx.x * blockDim.x + threadIdx.x;
  if (f < F) {
    float s = 0.f;
    for (int c = 0; c < C; ++c) s += W[f * C + c] * a[c];
    v[f] = s;
  }
}

// hs[n,:] = (relu?)x[n,:] @ W ;  alpha[n] = hs[n,:] @ a
template <int F, int C, bool RELU_IN>
__global__ void k_hs(const float* __restrict__ x, const float* __restrict__ W,
                     const float* __restrict__ a, float* __restrict__ hs,
                     float* __restrict__ alpha, int N) {
  __shared__ float sW[F * C];
  __shared__ float sa[C];
  for (int i = threadIdx.x; i < F * C; i += blockDim.x) sW[i] = W[i];
  if (threadIdx.x < C) sa[threadIdx.x] = a[threadIdx.x];
  __syncthreads();
  int n = blockIdx.x * blockDim.x + threadIdx.x;
  if (n >= N) return;
  float acc[C];
#pragma unroll
  for (int c = 0; c < C; ++c) acc[c] = 0.f;
  const float* xr = x + (size_t)n * F;
#pragma unroll 4
  for (int f = 0; f < F; ++f) {
    float xv = xr[f];
    if (RELU_IN) xv = fmaxf(xv, 0.f);
#pragma unroll
    for (int c = 0; c < C; ++c) acc[c] += xv * sW[f * C + c];
  }
  float al = 0.f;
#pragma unroll
  for (int c = 0; c < C; ++c) {
    hs[(size_t)n * C + c] = acc[c];
    al += acc[c] * sa[c];
  }
  alpha[n] = al;
}

// alpha[n] = (relu?)x[n,:] @ v
template <int F, bool RELU_IN>
__global__ void k_ad(const float* __restrict__ x, const float* __restrict__ v,
                     float* __restrict__ alpha, int N) {
  __shared__ float sv[F];
  if (threadIdx.x < F) sv[threadIdx.x] = v[threadIdx.x];
  __syncthreads();
  int n = blockIdx.x * blockDim.x + threadIdx.x;
  if (n >= N) return;
  const float* xr = x + (size_t)n * F;
  float s = 0.f;
#pragma unroll 4
  for (int f = 0; f < F; ++f) {
    float xv = xr[f];
    if (RELU_IN) xv = fmaxf(xv, 0.f);
    s += xv * sv[f];
  }
  alpha[n] = s;
}

// s[dst] += exp(leakyrelu(as[src]+ad[dst]))
__global__ void k_edge_sum(const int* __restrict__ src, const int* __restrict__ dst,
                           const float* __restrict__ as, const float* __restrict__ ad,
                           float* __restrict__ ssum, int nE) {
  int i = blockIdx.x * blockDim.x + threadIdx.x;
  if (i >= nE) return;
  int si = src[i], di = dst[i];
  float e = lrelu(as[si] + ad[di]);
  atomicAdd(&ssum[di], expf(e));
}

// out[dst,:] += (exp(e)/s[dst]) * hs[src,:]
template <int C>
__global__ void k_edge_accum(const int* __restrict__ src, const int* __restrict__ dst,
                             const float* __restrict__ as, const float* __restrict__ ad,
                             const float* __restrict__ ssum, const float* __restrict__ hs,
                             float* __restrict__ out, int nE) {
  int i = blockIdx.x * blockDim.x + threadIdx.x;
  if (i >= nE) return;
  int si = src[i], di = dst[i];
  float e = lrelu(as[si] + ad[di]);
  float al = expf(e) / (ssum[di] + 1e-16f);
  const float* h = hs + (size_t)si * C;
  float* o = out + (size_t)di * C;
#pragma unroll
  for (int c = 0; c < C; ++c) atomicAdd(&o[c], al * h[c]);
}

// out[n*C+c] = b[c]
template <int C>
__global__ void k_init_bias(float* __restrict__ out, const float* __restrict__ b, int N) {
  int i = blockIdx.x * blockDim.x + threadIdx.x;
  if (i < N * C) out[i] = b[i % C];
}

extern "C" void kernel_launch(void* const* d_in, const int* in_sizes, int n_in,
                              void* d_out, int out_size, void* d_ws, size_t ws_size,
                              hipStream_t stream) {
  const int NU = 200000, NB = 50000;
  const float* x_user  = (const float*)d_in[0];
  const float* x_badge = (const float*)d_in[1];
  const int* ub_src = (const int*)d_in[2];
  const int* ub_dst = (const int*)d_in[3];
  const int* bu_src = (const int*)d_in[4];
  const int* bu_dst = (const int*)d_in[5];
  const int nE = in_sizes[2];

  const float* W1_ub_s = (const float*)d_in[8];
  const float* W1_ub_d = (const float*)d_in[9];
  const float* a1_ub_s = (const float*)d_in[10];
  const float* a1_ub_d = (const float*)d_in[11];
  const float* b1_ub   = (const float*)d_in[12];
  const float* W2_ub_s = (const float*)d_in[13];
  const float* W2_ub_d = (const float*)d_in[14];
  const float* a2_ub_s = (const float*)d_in[15];
  const float* a2_ub_d = (const float*)d_in[16];
  const float* b2_ub   = (const float*)d_in[17];
  const float* W1_bu_s = (const float*)d_in[18];
  const float* W1_bu_d = (const float*)d_in[19];
  const float* a1_bu_s = (const float*)d_in[20];
  const float* a1_bu_d = (const float*)d_in[21];
  const float* b1_bu   = (const float*)d_in[22];
  const float* W2_bu_s = (const float*)d_in[23];
  const float* W2_bu_d = (const float*)d_in[24];
  const float* a2_bu_s = (const float*)d_in[25];
  const float* a2_bu_d = (const float*)d_in[26];
  const float* b2_bu   = (const float*)d_in[27];

  float* ws = (float*)d_ws;
  size_t off = 0;
  auto alloc = [&](size_t n) { float* p = ws + off; off += n; return p; };
  float* hs_u1  = alloc((size_t)NU * 16);
  float* hs_b1  = alloc((size_t)NB * 16);
  float* hu     = alloc((size_t)NU * 16);
  float* hb     = alloc((size_t)NB * 16);
  float* as_u1  = alloc(NU);
  float* ad_b1  = alloc(NB);
  float* s_b1   = alloc(NB);
  float* as_b1  = alloc(NB);
  float* ad_u1  = alloc(NU);
  float* s_u1   = alloc(NU);
  float* hs2_ub = alloc((size_t)NU * 2);
  float* as2_ub = alloc(NU);
  float* ad2_ub = alloc(NB);
  float* s2_b   = alloc(NB);
  float* hs2_bu = alloc((size_t)NB * 2);
  float* as2_bu = alloc(NB);
  float* ad2_bu = alloc(NU);
  float* s2_u   = alloc(NU);
  float* v1_ub  = alloc(64);
  float* v1_bu  = alloc(64);
  float* v2_ub  = alloc(16);
  float* v2_bu  = alloc(16);

  float* ou = (float*)d_out;                   // [NU,2]
  float* ob = (float*)d_out + (size_t)NU * 2;  // [NB,2]

  dim3 blk(256);
  auto g = [](int n) { return dim3((n + 255) / 256); };
  dim3 eg((nE + 255) / 256);

  // ===== layer 1, ub: src=user, dst=badge -> hb =====
  k_hs<64, 16, false><<<g(NU), blk, 0, stream>>>(x_user, W1_ub_s, a1_ub_s, hs_u1, as_u1, NU);
  k_wa<<<dim3(1), dim3(64), 0, stream>>>(W1_ub_d, a1_ub_d, v1_ub, 64, 16);
  k_ad<64, false><<<g(NB), blk, 0, stream>>>(x_badge, v1_ub, ad_b1, NB);
  hipMemsetAsync(s_b1, 0, NB * sizeof(float), stream);
  k_edge_sum<<<eg, blk, 0, stream>>>(ub_src, ub_dst, as_u1, ad_b1, s_b1, nE);
  k_init_bias<16><<<g(NB * 16), blk, 0, stream>>>(hb, b1_ub, NB);
  k_edge_accum<16><<<eg, blk, 0, stream>>>(ub_src, ub_dst, as_u1, ad_b1, s_b1, hs_u1, hb, nE);

  // ===== layer 1, bu: src=badge, dst=user -> hu =====
  k_hs<64, 16, false><<<g(NB), blk, 0, stream>>>(x_badge, W1_bu_s, a1_bu_s, hs_b1, as_b1, NB);
  k_wa<<<dim3(1), dim3(64), 0, stream>>>(W1_bu_d, a1_bu_d, v1_bu, 64, 16);
  k_ad<64, false><<<g(NU), blk, 0, stream>>>(x_user, v1_bu, ad_u1, NU);
  hipMemsetAsync(s_u1, 0, NU * sizeof(float), stream);
  k_edge_sum<<<eg, blk, 0, stream>>>(bu_src, bu_dst, as_b1, ad_u1, s_u1, nE);
  k_init_bias<16><<<g(NU * 16), blk, 0, stream>>>(hu, b1_bu, NU);
  k_edge_accum<16><<<eg, blk, 0, stream>>>(bu_src, bu_dst, as_b1, ad_u1, s_u1, hs_b1, hu, nE);

  // layer-1 outputs need relu before layer 2; folded into consumers (RELU_IN).

  // ===== layer 2, ub: src=relu(hu), dst=relu(hb) -> ob =====
  k_hs<16, 2, true><<<g(NU), blk, 0, stream>>>(hu, W2_ub_s, a2_ub_s, hs2_ub, as2_ub, NU);
  k_wa<<<dim3(1), dim3(16), 0, stream>>>(W2_ub_d, a2_ub_d, v2_ub, 16, 2);
  k_ad<16, true><<<g(NB), blk, 0, stream>>>(hb, v2_ub, ad2_ub, NB);
  hipMemsetAsync(s2_b, 0, NB * sizeof(float), stream);
  k_edge_sum<<<eg, blk, 0, stream>>>(ub_src, ub_dst, as2_ub, ad2_ub, s2_b, nE);
  k_init_bias<2><<<g(NB * 2), blk, 0, stream>>>(ob, b2_ub, NB);
  k_edge_accum<2><<<eg, blk, 0, stream>>>(ub_src, ub_dst, as2_ub, ad2_ub, s2_b, hs2_ub, ob, nE);

  // ===== layer 2, bu: src=relu(hb), dst=relu(hu) -> ou =====
  k_hs<16, 2, true><<<g(NB), blk, 0, stream>>>(hb, W2_bu_s, a2_bu_s, hs2_bu, as2_bu, NB);
  k_wa<<<dim3(1), dim3(16), 0, stream>>>(W2_bu_d, a2_bu_d, v2_bu, 16, 2);
  k_ad<16, true><<<g(NU), blk, 0, stream>>>(hu, v2_bu, ad2_bu, NU);
  hipMemsetAsync(s2_u, 0, NU * sizeof(float), stream);
  k_edge_sum<<<eg, blk, 0, stream>>>(bu_src, bu_dst, as2_bu, ad2_bu, s2_u, nE);
  k_init_bias<2><<<g(NU * 2), blk, 0, stream>>>(ou, b2_bu, NU);
  k_edge_accum<2><<<eg, blk, 0, stream>>>(bu_src, bu_dst, as2_bu, ad2_bu, s2_u, hs2_bu, ou, nE);
}

// Round 3
// 2010.496 us; speedup vs baseline: 5.2645x; 5.2645x over previous
//
#include <hip/hip_runtime.h>

// HeteroGNN: 2-layer bipartite single-head GAT (users<->badges).
// R3: replace per-edge scatter atomics (19.5 G atomic/s ceiling, 2.5 GB
// memory-side WRITE per pass) with CSR build + gather-side fused softmax
// reduction. CSR built per launch (hist + scan + scatter), amortized over
// both layers. Gather computes sum(exp) and sum(exp*hs) in one pass.

#define NEG_SLOPE 0.2f
#define SCAN_CH 2048

__device__ __forceinline__ float lrelu(float x) { return x > 0.f ? x : NEG_SLOPE * x; }

// ---------------- dense node kernels ----------------

// v[f] = sum_c W[f*C+c] * a[c]
__global__ void k_wa(const float* __restrict__ W, const float* __restrict__ a,
                     float* __restrict__ v, int F, int C) {
  int f = blockIdx.x * blockDim.x + threadIdx.x;
  if (f < F) {
    float s = 0.f;
    for (int c = 0; c < C; ++c) s += W[f * C + c] * a[c];
    v[f] = s;
  }
}

// hs[n,:] = (relu?)x[n,:] @ W ;  alpha[n] = hs[n,:] @ a
template <int F, int C, bool RELU_IN>
__global__ void k_hs(const float* __restrict__ x, const float* __restrict__ W,
                     const float* __restrict__ a, float* __restrict__ hs,
                     float* __restrict__ alpha, int N) {
  __shared__ float sW[F * C];
  __shared__ float sa[C];
  for (int i = threadIdx.x; i < F * C; i += blockDim.x) sW[i] = W[i];
  if (threadIdx.x < C) sa[threadIdx.x] = a[threadIdx.x];
  __syncthreads();
  int n = blockIdx.x * blockDim.x + threadIdx.x;
  if (n >= N) return;
  float acc[C];
#pragma unroll
  for (int c = 0; c < C; ++c) acc[c] = 0.f;
  const float* xr = x + (size_t)n * F;
#pragma unroll 4
  for (int f = 0; f < F; ++f) {
    float xv = xr[f];
    if (RELU_IN) xv = fmaxf(xv, 0.f);
#pragma unroll
    for (int c = 0; c < C; ++c) acc[c] += xv * sW[f * C + c];
  }
  float al = 0.f;
#pragma unroll
  for (int c = 0; c < C; ++c) {
    hs[(size_t)n * C + c] = acc[c];
    al += acc[c] * sa[c];
  }
  alpha[n] = al;
}

// alpha[n] = (relu?)x[n,:] @ v
template <int F, bool RELU_IN>
__global__ void k_ad(const float* __restrict__ x, const float* __restrict__ v,
                     float* __restrict__ alpha, int N) {
  __shared__ float sv[F];
  if (threadIdx.x < F) sv[threadIdx.x] = v[threadIdx.x];
  __syncthreads();
  int n = blockIdx.x * blockDim.x + threadIdx.x;
  if (n >= N) return;
  const float* xr = x + (size_t)n * F;
  float s = 0.f;
#pragma unroll 4
  for (int f = 0; f < F; ++f) {
    float xv = xr[f];
    if (RELU_IN) xv = fmaxf(xv, 0.f);
    s += xv * sv[f];
  }
  alpha[n] = s;
}

// ---------------- CSR build ----------------

__global__ void k_hist(const int* __restrict__ dst, int* __restrict__ deg, int nE) {
  int i = blockIdx.x * blockDim.x + threadIdx.x;
  if (i < nE) atomicAdd(&deg[dst[i]], 1);
}

// chunk partial sums: csum[t] = sum(deg[t*chunk : (t+1)*chunk])
__global__ void k_chunk_sum(const int* __restrict__ deg, int* __restrict__ csum,
                            int N, int chunk) {
  int t = blockIdx.x * blockDim.x + threadIdx.x;
  if (t >= SCAN_CH) return;
  int beg = t * chunk, end = min(beg + chunk, N);
  int s = 0;
  for (int i = beg; i < end; ++i) s += deg[i];
  csum[t] = s;
}

// single-block exclusive scan of csum[SCAN_CH] (1024 threads, 2 items each)
__global__ void k_scan_block(int* __restrict__ csum) {
  __shared__ int lds[1024];
  int t = threadIdx.x;
  int a = csum[2 * t], b = csum[2 * t + 1];
  int tot = a + b;
  lds[t] = tot;
  __syncthreads();
  for (int off = 1; off < 1024; off <<= 1) {
    int v = (t >= off) ? lds[t - off] : 0;
    __syncthreads();
    lds[t] += v;
    __syncthreads();
  }
  int excl = lds[t] - tot;
  csum[2 * t] = excl;
  csum[2 * t + 1] = excl + a;
}

// per-chunk serial exclusive scan -> rp, cursor copy; last writes rp[N]
__global__ void k_chunk_scan(const int* __restrict__ deg, const int* __restrict__ csum,
                             int* __restrict__ rp, int* __restrict__ cur,
                             int N, int chunk) {
  int t = blockIdx.x * blockDim.x + threadIdx.x;
  if (t >= SCAN_CH) return;
  int beg = t * chunk, end = min(beg + chunk, N);
  int run = csum[t];
  for (int i = beg; i < end; ++i) {
    rp[i] = run;
    cur[i] = run;
    run += deg[i];
  }
  if (end == N) rp[N] = run;  // trailing threads all write total E (benign)
}

__global__ void k_scatter(const int* __restrict__ src, const int* __restrict__ dst,
                          int* __restrict__ cur, int* __restrict__ col, int nE) {
  int i = blockIdx.x * blockDim.x + threadIdx.x;
  if (i < nE) {
    int p = atomicAdd(&cur[dst[i]], 1);
    col[p] = src[i];
  }
}

// ---------------- fused gather (softmax + aggregate + bias) ----------------
// GROUP = C*ESPLIT lanes per dst node: lane%C = channel, lane/C = edge stride.
template <int C, int ESPLIT>
__global__ void k_gather(const int* __restrict__ rp, const int* __restrict__ col,
                         const float* __restrict__ as, const float* __restrict__ ad,
                         const float* __restrict__ hs, const float* __restrict__ b,
                         float* __restrict__ out, int N) {
  constexpr int GROUP = C * ESPLIT;
  int t = blockIdx.x * blockDim.x + threadIdx.x;
  int n = t / GROUP;
  if (n >= N) return;
  int lane = t % GROUP;
  int c = lane % C;
  int j = lane / C;
  int beg = rp[n], end = rp[n + 1];
  float adv = ad[n];
  float acc = 0.f, se = 0.f;
  for (int k = beg + j; k < end; k += ESPLIT) {
    int s = col[k];
    float w = __expf(lrelu(as[s] + adv));
    se += w;
    acc += w * hs[(size_t)s * C + c];
  }
#pragma unroll
  for (int m = C; m < GROUP; m <<= 1) {
    acc += __shfl_xor(acc, m, GROUP);
    se += __shfl_xor(se, m, GROUP);
  }
  if (j == 0) out[(size_t)n * C + c] = acc / (se + 1e-16f) + b[c];
}

extern "C" void kernel_launch(void* const* d_in, const int* in_sizes, int n_in,
                              void* d_out, int out_size, void* d_ws, size_t ws_size,
                              hipStream_t stream) {
  const int NU = 200000, NB = 50000;
  const float* x_user  = (const float*)d_in[0];
  const float* x_badge = (const float*)d_in[1];
  const int* ub_src = (const int*)d_in[2];
  const int* ub_dst = (const int*)d_in[3];
  const int* bu_src = (const int*)d_in[4];
  const int* bu_dst = (const int*)d_in[5];
  const int nE = in_sizes[2];

  const float* W1_ub_s = (const float*)d_in[8];
  const float* W1_ub_d = (const float*)d_in[9];
  const float* a1_ub_s = (const float*)d_in[10];
  const float* a1_ub_d = (const float*)d_in[11];
  const float* b1_ub   = (const float*)d_in[12];
  const float* W2_ub_s = (const float*)d_in[13];
  const float* W2_ub_d = (const float*)d_in[14];
  const float* a2_ub_s = (const float*)d_in[15];
  const float* a2_ub_d = (const float*)d_in[16];
  const float* b2_ub   = (const float*)d_in[17];
  const float* W1_bu_s = (const float*)d_in[18];
  const float* W1_bu_d = (const float*)d_in[19];
  const float* a1_bu_s = (const float*)d_in[20];
  const float* a1_bu_d = (const float*)d_in[21];
  const float* b1_bu   = (const float*)d_in[22];
  const float* W2_bu_s = (const float*)d_in[23];
  const float* W2_bu_d = (const float*)d_in[24];
  const float* a2_bu_s = (const float*)d_in[25];
  const float* a2_bu_d = (const float*)d_in[26];
  const float* b2_bu   = (const float*)d_in[27];

  // ---- workspace carve-up ----
  char* wsb = (char*)d_ws;
  size_t off = 0;
  auto ialloc = [&](size_t n) { int* p = (int*)(wsb + off); off += n * 4; return p; };
  auto falloc = [&](size_t n) { float* p = (float*)(wsb + off); off += n * 4; return p; };
  // CSR (ub: dst=badge, bu: dst=user)
  int* deg_ub = ialloc(NB);       // contiguous with deg_bu for one memset
  int* deg_bu = ialloc(NU);
  int* rp_ub  = ialloc(NB + 1);
  int* cur_ub = ialloc(NB);
  int* col_ub = ialloc(nE);
  int* rp_bu  = ialloc(NU + 1);
  int* cur_bu = ialloc(NU);
  int* col_bu = ialloc(nE);
  int* csum_a = ialloc(SCAN_CH);
  int* csum_b = ialloc(SCAN_CH);
  // dense intermediates
  float* hs_u1  = falloc((size_t)NU * 16);
  float* hs_b1  = falloc((size_t)NB * 16);
  float* hu     = falloc((size_t)NU * 16);
  float* hb     = falloc((size_t)NB * 16);
  float* as_u1  = falloc(NU);
  float* ad_b1  = falloc(NB);
  float* as_b1  = falloc(NB);
  float* ad_u1  = falloc(NU);
  float* hs2_ub = falloc((size_t)NU * 2);
  float* as2_ub = falloc(NU);
  float* ad2_ub = falloc(NB);
  float* hs2_bu = falloc((size_t)NB * 2);
  float* as2_bu = falloc(NB);
  float* ad2_bu = falloc(NU);
  float* v1_ub  = falloc(64);
  float* v1_bu  = falloc(64);
  float* v2_ub  = falloc(16);
  float* v2_bu  = falloc(16);

  float* ou = (float*)d_out;                   // [NU,2]
  float* ob = (float*)d_out + (size_t)NU * 2;  // [NB,2]

  dim3 blk(256);
  auto g = [](int n) { return dim3((n + 255) / 256); };
  dim3 eg((nE + 255) / 256);
  const int chunk_b = (NB + SCAN_CH - 1) / SCAN_CH;
  const int chunk_u = (NU + SCAN_CH - 1) / SCAN_CH;
  dim3 sg(SCAN_CH / 256);

  // ===== CSR build for both graphs =====
  hipMemsetAsync(deg_ub, 0, (size_t)(NB + NU) * 4, stream);
  k_hist<<<eg, blk, 0, stream>>>(ub_dst, deg_ub, nE);
  k_hist<<<eg, blk, 0, stream>>>(bu_dst, deg_bu, nE);
  k_chunk_sum<<<sg, blk, 0, stream>>>(deg_ub, csum_a, NB, chunk_b);
  k_chunk_sum<<<sg, blk, 0, stream>>>(deg_bu, csum_b, NU, chunk_u);
  k_scan_block<<<dim3(1), dim3(1024), 0, stream>>>(csum_a);
  k_scan_block<<<dim3(1), dim3(1024), 0, stream>>>(csum_b);
  k_chunk_scan<<<sg, blk, 0, stream>>>(deg_ub, csum_a, rp_ub, cur_ub, NB, chunk_b);
  k_chunk_scan<<<sg, blk, 0, stream>>>(deg_bu, csum_b, rp_bu, cur_bu, NU, chunk_u);
  k_scatter<<<eg, blk, 0, stream>>>(ub_src, ub_dst, cur_ub, col_ub, nE);
  k_scatter<<<eg, blk, 0, stream>>>(bu_src, bu_dst, cur_bu, col_bu, nE);

  // ===== layer 1 node transforms =====
  k_hs<64, 16, false><<<g(NU), blk, 0, stream>>>(x_user, W1_ub_s, a1_ub_s, hs_u1, as_u1, NU);
  k_wa<<<dim3(1), dim3(64), 0, stream>>>(W1_ub_d, a1_ub_d, v1_ub, 64, 16);
  k_ad<64, false><<<g(NB), blk, 0, stream>>>(x_badge, v1_ub, ad_b1, NB);
  k_hs<64, 16, false><<<g(NB), blk, 0, stream>>>(x_badge, W1_bu_s, a1_bu_s, hs_b1, as_b1, NB);
  k_wa<<<dim3(1), dim3(64), 0, stream>>>(W1_bu_d, a1_bu_d, v1_bu, 64, 16);
  k_ad<64, false><<<g(NU), blk, 0, stream>>>(x_user, v1_bu, ad_u1, NU);

  // ===== layer 1 fused gathers (softmax + aggregate + bias) =====
  k_gather<16, 1><<<g(NB * 16), blk, 0, stream>>>(rp_ub, col_ub, as_u1, ad_b1, hs_u1, b1_ub, hb, NB);
  k_gather<16, 1><<<g(NU * 16), blk, 0, stream>>>(rp_bu, col_bu, as_b1, ad_u1, hs_b1, b1_bu, hu, NU);

  // ===== layer 2 node transforms (relu folded via RELU_IN) =====
  k_hs<16, 2, true><<<g(NU), blk, 0, stream>>>(hu, W2_ub_s, a2_ub_s, hs2_ub, as2_ub, NU);
  k_wa<<<dim3(1), dim3(16), 0, stream>>>(W2_ub_d, a2_ub_d, v2_ub, 16, 2);
  k_ad<16, true><<<g(NB), blk, 0, stream>>>(hb, v2_ub, ad2_ub, NB);
  k_hs<16, 2, true><<<g(NB), blk, 0, stream>>>(hb, W2_bu_s, a2_bu_s, hs2_bu, as2_bu, NB);
  k_wa<<<dim3(1), dim3(16), 0, stream>>>(W2_bu_d, a2_bu_d, v2_bu, 16, 2);
  k_ad<16, true><<<g(NU), blk, 0, stream>>>(hu, v2_bu, ad2_bu, NU);

  // ===== layer 2 fused gathers =====
  k_gather<2, 4><<<g(NB * 8), blk, 0, stream>>>(rp_ub, col_ub, as2_ub, ad2_ub, hs2_ub, b2_ub, ob, NB);
  k_gather<2, 4><<<g(NU * 8), blk, 0, stream>>>(rp_bu, col_bu, as2_bu, ad2_bu, hs2_bu, b2_bu, ou, NU);
}

// Round 4
// 1042.399 us; speedup vs baseline: 10.1538x; 1.9287x over previous
//
#include <hip/hip_runtime.h>

// HeteroGNN: 2-layer bipartite single-head GAT (users<->badges).
// R4: CSR build via two-level counting sort with ZERO per-edge global atomics
// (R3's k_hist+k_scatter = 10M global atomics @19.5G/s = ~1.4ms of 2.0ms).
//   pass 1: coarse bucket partition (LDS hist + block-aggregated range
//           reservation + LDS cursors), edges packed (dst,src) into padded
//           per-bucket regions.
//   pass 2: one block per bucket: LDS hist over local nodes -> LDS scan ->
//           rp + col placement with LDS cursors. Contiguous writes.
// Gathers (fused softmax+aggregate+bias) unchanged from R3.

#define NEG_SLOPE 0.2f
#define NPART_BLOCKS 1024

__device__ __forceinline__ float lrelu(float x) { return x > 0.f ? x : NEG_SLOPE * x; }

// ---------------- dense node kernels ----------------

__global__ void k_wa(const float* __restrict__ W, const float* __restrict__ a,
                     float* __restrict__ v, int F, int C) {
  int f = blockIdx.x * blockDim.x + threadIdx.x;
  if (f < F) {
    float s = 0.f;
    for (int c = 0; c < C; ++c) s += W[f * C + c] * a[c];
    v[f] = s;
  }
}

template <int F, int C, bool RELU_IN>
__global__ void k_hs(const float* __restrict__ x, const float* __restrict__ W,
                     const float* __restrict__ a, float* __restrict__ hs,
                     float* __restrict__ alpha, int N) {
  __shared__ float sW[F * C];
  __shared__ float sa[C];
  for (int i = threadIdx.x; i < F * C; i += blockDim.x) sW[i] = W[i];
  if (threadIdx.x < C) sa[threadIdx.x] = a[threadIdx.x];
  __syncthreads();
  int n = blockIdx.x * blockDim.x + threadIdx.x;
  if (n >= N) return;
  float acc[C];
#pragma unroll
  for (int c = 0; c < C; ++c) acc[c] = 0.f;
  const float* xr = x + (size_t)n * F;
#pragma unroll 4
  for (int f = 0; f < F; ++f) {
    float xv = xr[f];
    if (RELU_IN) xv = fmaxf(xv, 0.f);
#pragma unroll
    for (int c = 0; c < C; ++c) acc[c] += xv * sW[f * C + c];
  }
  float al = 0.f;
#pragma unroll
  for (int c = 0; c < C; ++c) {
    hs[(size_t)n * C + c] = acc[c];
    al += acc[c] * sa[c];
  }
  alpha[n] = al;
}

template <int F, bool RELU_IN>
__global__ void k_ad(const float* __restrict__ x, const float* __restrict__ v,
                     float* __restrict__ alpha, int N) {
  __shared__ float sv[F];
  if (threadIdx.x < F) sv[threadIdx.x] = v[threadIdx.x];
  __syncthreads();
  int n = blockIdx.x * blockDim.x + threadIdx.x;
  if (n >= N) return;
  const float* xr = x + (size_t)n * F;
  float s = 0.f;
#pragma unroll 4
  for (int f = 0; f < F; ++f) {
    float xv = xr[f];
    if (RELU_IN) xv = fmaxf(xv, 0.f);
    s += xv * sv[f];
  }
  alpha[n] = s;
}

// ---------------- CSR build: two-level counting sort ----------------

// pass 1: partition edges into coarse buckets (bucket = dst >> shift).
// Per-edge work uses only LDS atomics; one global atomicAdd per (block,bucket).
__global__ void k_partition(const int* __restrict__ src, const int* __restrict__ dst,
                            int nE, int shift, int nbuck,
                            unsigned long long* __restrict__ part, int cap,
                            int* __restrict__ bcnt) {
  __shared__ int h[256];      // per-block bucket counts, then cursors
  __shared__ int basez[256];  // reserved global base per bucket
  int per = (nE + gridDim.x - 1) / gridDim.x;
  int beg = blockIdx.x * per;
  int end = min(beg + per, nE);
  for (int i = threadIdx.x; i < 256; i += blockDim.x) h[i] = 0;
  __syncthreads();
  for (int i = beg + threadIdx.x; i < end; i += blockDim.x)
    atomicAdd(&h[dst[i] >> shift], 1);  // LDS atomic
  __syncthreads();
  for (int i = threadIdx.x; i < 256; i += blockDim.x) {
    int c = h[i];
    basez[i] = (i < nbuck && c > 0) ? atomicAdd(&bcnt[i], c) : 0;  // aggregated
    h[i] = 0;  // reuse as cursor
  }
  __syncthreads();
  for (int i = beg + threadIdx.x; i < end; i += blockDim.x) {
    int d = dst[i];
    int bu = d >> shift;
    int r = atomicAdd(&h[bu], 1);  // LDS cursor
    int p = basez[bu] + r;
    if (p < cap)  // ~10-sigma margin; clamp only guards OOB
      part[(size_t)bu * cap + p] =
          ((unsigned long long)(unsigned)d << 32) | (unsigned)src[i];
  }
}

// exclusive scan of bcnt[nbuck<=256] -> bbase
__global__ void k_scanb(const int* __restrict__ bcnt, int* __restrict__ bbase, int nbuck) {
  __shared__ int lds[256];
  int t = threadIdx.x;
  int v = (t < nbuck) ? bcnt[t] : 0;
  lds[t] = v;
  __syncthreads();
  for (int off = 1; off < 256; off <<= 1) {
    int u = (t >= off) ? lds[t - off] : 0;
    __syncthreads();
    lds[t] += u;
    __syncthreads();
  }
  if (t < nbuck) bbase[t] = lds[t] - v;
}

// pass 2: one block per bucket -> rp + col (all per-edge atomics in LDS)
template <int NPB>
__global__ void k_bucket_csr(const unsigned long long* __restrict__ part,
                             const int* __restrict__ bcnt, const int* __restrict__ bbase,
                             int cap, int* __restrict__ rp, int* __restrict__ col,
                             int N, int nbuck) {
  constexpr int ITEMS = NPB / 256;
  __shared__ int hist[NPB];
  __shared__ int start[NPB];  // scanned offsets, then cursors
  __shared__ int ps[256];
  int b = blockIdx.x;
  int t = threadIdx.x;
  int node0 = b * NPB;
  int cnt = min(bcnt[b], cap);
  int base = bbase[b];
  const unsigned long long* pp = part + (size_t)b * cap;
  for (int i = t; i < NPB; i += 256) hist[i] = 0;
  __syncthreads();
  for (int i = t; i < cnt; i += 256) {
    int d = (int)(pp[i] >> 32);
    atomicAdd(&hist[d - node0], 1);
  }
  __syncthreads();
  // block exclusive scan of hist -> start
  int tp[ITEMS];
  int sum = 0;
#pragma unroll
  for (int k = 0; k < ITEMS; ++k) { tp[k] = sum; sum += hist[t * ITEMS + k]; }
  ps[t] = sum;
  __syncthreads();
  for (int off = 1; off < 256; off <<= 1) {
    int u = (t >= off) ? ps[t - off] : 0;
    __syncthreads();
    ps[t] += u;
    __syncthreads();
  }
  int te = ps[t] - sum;
#pragma unroll
  for (int k = 0; k < ITEMS; ++k) start[t * ITEMS + k] = te + tp[k];
  __syncthreads();
  for (int i = t; i < NPB; i += 256) {
    int n = node0 + i;
    if (n < N) rp[n] = base + start[i];
  }
  if (b == nbuck - 1 && t == 0) rp[N] = base + cnt;
  __syncthreads();  // rp reads of start[] before cursor mutation
  for (int i = t; i < cnt; i += 256) {
    unsigned long long e = pp[i];
    int dl = (int)(e >> 32) - node0;
    int r = atomicAdd(&start[dl], 1);  // LDS cursor
    col[base + r] = (int)(e & 0xffffffffULL);
  }
}

// ---------------- fused gather (softmax + aggregate + bias) ----------------
template <int C, int ESPLIT>
__global__ void k_gather(const int* __restrict__ rp, const int* __restrict__ col,
                         const float* __restrict__ as, const float* __restrict__ ad,
                         const float* __restrict__ hs, const float* __restrict__ b,
                         float* __restrict__ out, int N) {
  constexpr int GROUP = C * ESPLIT;
  int t = blockIdx.x * blockDim.x + threadIdx.x;
  int n = t / GROUP;
  if (n >= N) return;
  int lane = t % GROUP;
  int c = lane % C;
  int j = lane / C;
  int beg = rp[n], end = rp[n + 1];
  float adv = ad[n];
  float acc = 0.f, se = 0.f;
  for (int k = beg + j; k < end; k += ESPLIT) {
    int s = col[k];
    float w = __expf(lrelu(as[s] + adv));
    se += w;
    acc += w * hs[(size_t)s * C + c];
  }
#pragma unroll
  for (int m = C; m < GROUP; m <<= 1) {
    acc += __shfl_xor(acc, m, GROUP);
    se += __shfl_xor(se, m, GROUP);
  }
  if (j == 0) out[(size_t)n * C + c] = acc / (se + 1e-16f) + b[c];
}

extern "C" void kernel_launch(void* const* d_in, const int* in_sizes, int n_in,
                              void* d_out, int out_size, void* d_ws, size_t ws_size,
                              hipStream_t stream) {
  const int NU = 200000, NB = 50000;
  const float* x_user  = (const float*)d_in[0];
  const float* x_badge = (const float*)d_in[1];
  const int* ub_src = (const int*)d_in[2];
  const int* ub_dst = (const int*)d_in[3];
  const int* bu_src = (const int*)d_in[4];
  const int* bu_dst = (const int*)d_in[5];
  const int nE = in_sizes[2];

  const float* W1_ub_s = (const float*)d_in[8];
  const float* W1_ub_d = (const float*)d_in[9];
  const float* a1_ub_s = (const float*)d_in[10];
  const float* a1_ub_d = (const float*)d_in[11];
  const float* b1_ub   = (const float*)d_in[12];
  const float* W2_ub_s = (const float*)d_in[13];
  const float* W2_ub_d = (const float*)d_in[14];
  const float* a2_ub_s = (const float*)d_in[15];
  const float* a2_ub_d = (const float*)d_in[16];
  const float* b2_ub   = (const float*)d_in[17];
  const float* W1_bu_s = (const float*)d_in[18];
  const float* W1_bu_d = (const float*)d_in[19];
  const float* a1_bu_s = (const float*)d_in[20];
  const float* a1_bu_d = (const float*)d_in[21];
  const float* b1_bu   = (const float*)d_in[22];
  const float* W2_bu_s = (const float*)d_in[23];
  const float* W2_bu_d = (const float*)d_in[24];
  const float* a2_bu_s = (const float*)d_in[25];
  const float* a2_bu_d = (const float*)d_in[26];
  const float* b2_bu   = (const float*)d_in[27];

  // bucket geometry: NPB=256 (shift 8) for dst=badge, NPB=1024 (shift 10) for dst=user
  const int nbk_ub = (NB + 255) / 256;      // 196
  const int nbk_bu = (NU + 1023) / 1024;    // 196
  // padded per-bucket capacity: mean + 8*sigma + 256 (~10 sigma margin)
  double m_ub = (double)nE * 256.0 / NB;
  double m_bu = (double)nE * 1024.0 / NU;
  int cap_ub = (int)(m_ub + 8.0 * sqrt(m_ub) + 256.0);
  int cap_bu = (int)(m_bu + 8.0 * sqrt(m_bu) + 256.0);
  size_t part_bytes = (size_t)8 *
      ((size_t)nbk_ub * cap_ub > (size_t)nbk_bu * cap_bu ? (size_t)nbk_ub * cap_ub
                                                         : (size_t)nbk_bu * cap_bu);

  // ---- workspace carve-up ----
  char* wsb = (char*)d_ws;
  size_t off = 0;
  auto ialloc = [&](size_t n) { int* p = (int*)(wsb + off); off += n * 4; return p; };
  int* rp_ub   = ialloc(NB + 1);
  int* rp_bu   = ialloc(NU + 1);
  int* col_ub  = ialloc(nE);
  int* col_bu  = ialloc(nE);
  int* bcnt_ub = ialloc(256);   // bcnt_ub+bcnt_bu contiguous: single memset
  int* bcnt_bu = ialloc(256);
  int* bbase_ub= ialloc(256);
  int* bbase_bu= ialloc(256);
  off = (off + 15) & ~(size_t)15;
  // UNION: part buffer (dead after pass 2 of bu) overlays node-feature arrays
  // (only written afterwards; stream is serial).
  char* pool = wsb + off;
  unsigned long long* part = (unsigned long long*)pool;
  size_t poff = 0;
  auto falloc = [&](size_t n) { float* p = (float*)(pool + poff); poff += n * 4; return p; };
  float* hs_u1  = falloc((size_t)NU * 16);
  float* hs_b1  = falloc((size_t)NB * 16);
  float* hu     = falloc((size_t)NU * 16);
  float* hb     = falloc((size_t)NB * 16);
  float* as_u1  = falloc(NU);
  float* ad_b1  = falloc(NB);
  float* as_b1  = falloc(NB);
  float* ad_u1  = falloc(NU);
  float* hs2_ub = falloc((size_t)NU * 2);
  float* as2_ub = falloc(NU);
  float* ad2_ub = falloc(NB);
  float* hs2_bu = falloc((size_t)NB * 2);
  float* as2_bu = falloc(NB);
  float* ad2_bu = falloc(NU);
  float* v1_ub  = falloc(64);
  float* v1_bu  = falloc(64);
  float* v2_ub  = falloc(16);
  float* v2_bu  = falloc(16);
  (void)part_bytes; (void)ws_size;

  float* ou = (float*)d_out;                   // [NU,2]
  float* ob = (float*)d_out + (size_t)NU * 2;  // [NB,2]

  dim3 blk(256);
  auto g = [](int n) { return dim3((n + 255) / 256); };

  // ===== CSR build (serialized per graph; part buffer reused) =====
  hipMemsetAsync(bcnt_ub, 0, 512 * 4, stream);
  k_partition<<<dim3(NPART_BLOCKS), blk, 0, stream>>>(ub_src, ub_dst, nE, 8, nbk_ub,
                                                      part, cap_ub, bcnt_ub);
  k_scanb<<<dim3(1), blk, 0, stream>>>(bcnt_ub, bbase_ub, nbk_ub);
  k_bucket_csr<256><<<dim3(nbk_ub), blk, 0, stream>>>(part, bcnt_ub, bbase_ub, cap_ub,
                                                      rp_ub, col_ub, NB, nbk_ub);
  k_partition<<<dim3(NPART_BLOCKS), blk, 0, stream>>>(bu_src, bu_dst, nE, 10, nbk_bu,
                                                      part, cap_bu, bcnt_bu);
  k_scanb<<<dim3(1), blk, 0, stream>>>(bcnt_bu, bbase_bu, nbk_bu);
  k_bucket_csr<1024><<<dim3(nbk_bu), blk, 0, stream>>>(part, cap_bu ? bcnt_bu : bcnt_bu,
                                                       bbase_bu, cap_bu,
                                                       rp_bu, col_bu, NU, nbk_bu);

  // ===== layer 1 node transforms (writes into union pool; part now dead) =====
  k_hs<64, 16, false><<<g(NU), blk, 0, stream>>>(x_user, W1_ub_s, a1_ub_s, hs_u1, as_u1, NU);
  k_wa<<<dim3(1), dim3(64), 0, stream>>>(W1_ub_d, a1_ub_d, v1_ub, 64, 16);
  k_ad<64, false><<<g(NB), blk, 0, stream>>>(x_badge, v1_ub, ad_b1, NB);
  k_hs<64, 16, false><<<g(NB), blk, 0, stream>>>(x_badge, W1_bu_s, a1_bu_s, hs_b1, as_b1, NB);
  k_wa<<<dim3(1), dim3(64), 0, stream>>>(W1_bu_d, a1_bu_d, v1_bu, 64, 16);
  k_ad<64, false><<<g(NU), blk, 0, stream>>>(x_user, v1_bu, ad_u1, NU);

  // ===== layer 1 fused gathers =====
  k_gather<16, 1><<<g(NB * 16), blk, 0, stream>>>(rp_ub, col_ub, as_u1, ad_b1, hs_u1, b1_ub, hb, NB);
  k_gather<16, 1><<<g(NU * 16), blk, 0, stream>>>(rp_bu, col_bu, as_b1, ad_u1, hs_b1, b1_bu, hu, NU);

  // ===== layer 2 node transforms (relu folded) =====
  k_hs<16, 2, true><<<g(NU), blk, 0, stream>>>(hu, W2_ub_s, a2_ub_s, hs2_ub, as2_ub, NU);
  k_wa<<<dim3(1), dim3(16), 0, stream>>>(W2_ub_d, a2_ub_d, v2_ub, 16, 2);
  k_ad<16, true><<<g(NB), blk, 0, stream>>>(hb, v2_ub, ad2_ub, NB);
  k_hs<16, 2, true><<<g(NB), blk, 0, stream>>>(hb, W2_bu_s, a2_bu_s, hs2_bu, as2_bu, NB);
  k_wa<<<dim3(1), dim3(16), 0, stream>>>(W2_bu_d, a2_bu_d, v2_bu, 16, 2);
  k_ad<16, true><<<g(NU), blk, 0, stream>>>(hu, v2_bu, ad2_bu, NU);

  // ===== layer 2 fused gathers =====
  k_gather<2, 4><<<g(NB * 8), blk, 0, stream>>>(rp_ub, col_ub, as2_ub, ad2_ub, hs2_ub, b2_ub, ob, NB);
  k_gather<2, 4><<<g(NU * 8), blk, 0, stream>>>(rp_bu, col_bu, as2_bu, ad2_bu, hs2_bu, b2_bu, ou, NU);
}

// Round 5
// 1003.360 us; speedup vs baseline: 10.5489x; 1.0389x over previous
//
#include <hip/hip_runtime.h>
#include <hip/hip_fp16.h>
#include <math.h>

// HeteroGNN: 2-layer bipartite single-head GAT (users<->badges).
// R5: attack the 400MB-FETCH layer-1 gathers (L2-capacity misses on random
// 64B hs-row gathers):
//   - hs stored fp16 for layer-1 gathers (rows 32B, tables halve)
//   - ub gather (hs_u1 6.4MB > 4MB L2) split into 4 src-shards of 1.6MB,
//     CSR sub-sorted by (dst, src-shard) in bucket pass; 4 sequential
//     dispatches each with an L2-resident hs slice; non-atomic partial
//     accumulation (dst-owned) + finalize.
//   - k_wa folded into k_ad (fewer launches).
// CSR build (zero per-edge global atomics) unchanged from R4.

#define NEG_SLOPE 0.2f
#define NPART_BLOCKS 1024
#define NS_UB 4
#define SHARD_DIV 50000

__device__ __forceinline__ float lrelu(float x) { return x > 0.f ? x : NEG_SLOPE * x; }

// ---------------- dense node kernels ----------------

// hs(half)[n,:] = x[n,:] @ W ;  alpha[n] = hs[n,:] @ a   (layer 1)
template <int F, int C>
__global__ void k_hs_h(const float* __restrict__ x, const float* __restrict__ W,
                       const float* __restrict__ a, __half* __restrict__ hs,
                       float* __restrict__ alpha, int N) {
  __shared__ float sW[F * C];
  __shared__ float sa[C];
  for (int i = threadIdx.x; i < F * C; i += blockDim.x) sW[i] = W[i];
  if (threadIdx.x < C) sa[threadIdx.x] = a[threadIdx.x];
  __syncthreads();
  int n = blockIdx.x * blockDim.x + threadIdx.x;
  if (n >= N) return;
  float acc[C];
#pragma unroll
  for (int c = 0; c < C; ++c) acc[c] = 0.f;
  const float* xr = x + (size_t)n * F;
#pragma unroll 4
  for (int f = 0; f < F; ++f) {
    float xv = xr[f];
#pragma unroll
    for (int c = 0; c < C; ++c) acc[c] += xv * sW[f * C + c];
  }
  float al = 0.f;
#pragma unroll
  for (int c = 0; c < C; ++c) {
    hs[(size_t)n * C + c] = __float2half(acc[c]);
    al += acc[c] * sa[c];
  }
  alpha[n] = al;
}

// hs(float)[n,:] = relu(x[n,:]) @ W ; alpha[n] = hs[n,:] @ a   (layer 2)
template <int F, int C, bool RELU_IN>
__global__ void k_hs(const float* __restrict__ x, const float* __restrict__ W,
                     const float* __restrict__ a, float* __restrict__ hs,
                     float* __restrict__ alpha, int N) {
  __shared__ float sW[F * C];
  __shared__ float sa[C];
  for (int i = threadIdx.x; i < F * C; i += blockDim.x) sW[i] = W[i];
  if (threadIdx.x < C) sa[threadIdx.x] = a[threadIdx.x];
  __syncthreads();
  int n = blockIdx.x * blockDim.x + threadIdx.x;
  if (n >= N) return;
  float acc[C];
#pragma unroll
  for (int c = 0; c < C; ++c) acc[c] = 0.f;
  const float* xr = x + (size_t)n * F;
#pragma unroll 4
  for (int f = 0; f < F; ++f) {
    float xv = xr[f];
    if (RELU_IN) xv = fmaxf(xv, 0.f);
#pragma unroll
    for (int c = 0; c < C; ++c) acc[c] += xv * sW[f * C + c];
  }
  float al = 0.f;
#pragma unroll
  for (int c = 0; c < C; ++c) {
    hs[(size_t)n * C + c] = acc[c];
    al += acc[c] * sa[c];
  }
  alpha[n] = al;
}

// alpha[n] = (relu?)x[n,:] @ (W @ a)   (k_wa folded in)
template <int F, bool RELU_IN>
__global__ void k_ad2(const float* __restrict__ x, const float* __restrict__ W,
                      const float* __restrict__ a, float* __restrict__ alpha,
                      int N, int C) {
  __shared__ float sv[F];
  if (threadIdx.x < F) {
    float s = 0.f;
    for (int c = 0; c < C; ++c) s += W[threadIdx.x * C + c] * a[c];
    sv[threadIdx.x] = s;
  }
  __syncthreads();
  int n = blockIdx.x * blockDim.x + threadIdx.x;
  if (n >= N) return;
  const float* xr = x + (size_t)n * F;
  float s = 0.f;
#pragma unroll 4
  for (int f = 0; f < F; ++f) {
    float xv = xr[f];
    if (RELU_IN) xv = fmaxf(xv, 0.f);
    s += xv * sv[f];
  }
  alpha[n] = s;
}

// ---------------- CSR build: two-level counting sort ----------------

__global__ void k_partition(const int* __restrict__ src, const int* __restrict__ dst,
                            int nE, int shift, int nbuck,
                            unsigned long long* __restrict__ part, int cap,
                            int* __restrict__ bcnt) {
  __shared__ int h[256];
  __shared__ int basez[256];
  int per = (nE + gridDim.x - 1) / gridDim.x;
  int beg = blockIdx.x * per;
  int end = min(beg + per, nE);
  for (int i = threadIdx.x; i < 256; i += blockDim.x) h[i] = 0;
  __syncthreads();
  for (int i = beg + threadIdx.x; i < end; i += blockDim.x)
    atomicAdd(&h[dst[i] >> shift], 1);
  __syncthreads();
  for (int i = threadIdx.x; i < 256; i += blockDim.x) {
    int c = h[i];
    basez[i] = (i < nbuck && c > 0) ? atomicAdd(&bcnt[i], c) : 0;
    h[i] = 0;
  }
  __syncthreads();
  for (int i = beg + threadIdx.x; i < end; i += blockDim.x) {
    int d = dst[i];
    int bu = d >> shift;
    int r = atomicAdd(&h[bu], 1);
    int p = basez[bu] + r;
    if (p < cap)
      part[(size_t)bu * cap + p] =
          ((unsigned long long)(unsigned)d << 32) | (unsigned)src[i];
  }
}

__global__ void k_scanb(const int* __restrict__ bcnt, int* __restrict__ bbase, int nbuck) {
  __shared__ int lds[256];
  int t = threadIdx.x;
  int v = (t < nbuck) ? bcnt[t] : 0;
  lds[t] = v;
  __syncthreads();
  for (int off = 1; off < 256; off <<= 1) {
    int u = (t >= off) ? lds[t - off] : 0;
    __syncthreads();
    lds[t] += u;
    __syncthreads();
  }
  if (t < nbuck) bbase[t] = lds[t] - v;
}

// pass 2: one block per bucket -> rp2 (stride NS, sub-sorted by src shard) + col
template <int NPB, int NS>
__global__ void k_bucket_csr(const unsigned long long* __restrict__ part,
                             const int* __restrict__ bcnt, const int* __restrict__ bbase,
                             int cap, int* __restrict__ rp2, int* __restrict__ col,
                             int N, int nbuck, int shard_div) {
  constexpr int NBINS = NPB * NS;
  constexpr int ITEMS = NBINS / 256;
  __shared__ int hist[NBINS];
  __shared__ int start[NBINS];
  __shared__ int ps[256];
  int b = blockIdx.x;
  int t = threadIdx.x;
  int node0 = b * NPB;
  int cnt = min(bcnt[b], cap);
  int base = bbase[b];
  const unsigned long long* pp = part + (size_t)b * cap;
  for (int i = t; i < NBINS; i += 256) hist[i] = 0;
  __syncthreads();
  for (int i = t; i < cnt; i += 256) {
    unsigned long long e = pp[i];
    int dl = (int)(e >> 32) - node0;
    int sh = (NS == 1) ? 0 : ((int)(e & 0xffffffffULL) / shard_div);
    atomicAdd(&hist[dl * NS + sh], 1);
  }
  __syncthreads();
  int tp[ITEMS];
  int sum = 0;
#pragma unroll
  for (int k = 0; k < ITEMS; ++k) { tp[k] = sum; sum += hist[t * ITEMS + k]; }
  ps[t] = sum;
  __syncthreads();
  for (int off = 1; off < 256; off <<= 1) {
    int u = (t >= off) ? ps[t - off] : 0;
    __syncthreads();
    ps[t] += u;
    __syncthreads();
  }
  int te = ps[t] - sum;
#pragma unroll
  for (int k = 0; k < ITEMS; ++k) start[t * ITEMS + k] = te + tp[k];
  __syncthreads();
  for (int i = t; i < NBINS; i += 256) {
    int node = node0 + i / NS;
    if (node < N) rp2[(size_t)node0 * NS + i] = base + start[i];
  }
  if (b == nbuck - 1 && t == 0) rp2[(size_t)N * NS] = base + cnt;
  __syncthreads();
  for (int i = t; i < cnt; i += 256) {
    unsigned long long e = pp[i];
    int sv = (int)(e & 0xffffffffULL);
    int dl = (int)(e >> 32) - node0;
    int sh = (NS == 1) ? 0 : (sv / shard_div);
    int r = atomicAdd(&start[dl * NS + sh], 1);
    col[base + r] = sv;
  }
}

// ---------------- gathers ----------------

// full-list fused gather (softmax + aggregate + bias); rp indexed with stride rs
template <int C, int ESPLIT, typename HT>
__global__ void k_gather(const int* __restrict__ rp, int rs, const int* __restrict__ col,
                         const float* __restrict__ as, const float* __restrict__ ad,
                         const HT* __restrict__ hs, const float* __restrict__ b,
                         float* __restrict__ out, int N) {
  constexpr int GROUP = C * ESPLIT;
  int t = blockIdx.x * blockDim.x + threadIdx.x;
  int n = t / GROUP;
  if (n >= N) return;
  int lane = t % GROUP;
  int c = lane % C;
  int j = lane / C;
  int beg = rp[(size_t)n * rs], end = rp[(size_t)(n + 1) * rs];
  float adv = ad[n];
  float acc = 0.f, se = 0.f;
  for (int k = beg + j; k < end; k += ESPLIT) {
    int s = col[k];
    float w = __expf(lrelu(as[s] + adv));
    se += w;
    acc += w * (float)hs[(size_t)s * C + c];
  }
#pragma unroll
  for (int m = C; m < GROUP; m <<= 1) {
    acc += __shfl_xor(acc, m, GROUP);
    se += __shfl_xor(se, m, GROUP);
  }
  if (j == 0) out[(size_t)n * C + c] = acc / (se + 1e-16f) + b[c];
}

// sharded partial gather: processes sub-segment (n, shard s); dst-owned RMW
template <int C>
__global__ void k_gpart(const int* __restrict__ rp2, const int* __restrict__ col,
                        const float* __restrict__ as, const float* __restrict__ ad,
                        const __half* __restrict__ hs, float* __restrict__ acc_g,
                        float* __restrict__ se_g, int N, int s, int first) {
  int t = blockIdx.x * blockDim.x + threadIdx.x;
  int n = t / C;
  if (n >= N) return;
  int c = t % C;
  int beg = rp2[(size_t)n * NS_UB + s], end = rp2[(size_t)n * NS_UB + s + 1];
  float adv = ad[n];
  float acc = 0.f, se = 0.f;
  for (int k = beg; k < end; ++k) {
    int sv = col[k];
    float w = __expf(lrelu(as[sv] + adv));
    se += w;
    acc += w * (float)hs[(size_t)sv * C + c];
  }
  size_t oi = (size_t)n * C + c;
  if (first) {
    acc_g[oi] = acc;
    if (c == 0) se_g[n] = se;
  } else {
    acc_g[oi] += acc;
    if (c == 0) se_g[n] += se;
  }
}

template <int C>
__global__ void k_gfin(const float* __restrict__ acc_g, const float* __restrict__ se_g,
                       const float* __restrict__ b, float* __restrict__ out, int N) {
  int t = blockIdx.x * blockDim.x + threadIdx.x;
  if (t >= N * C) return;
  int n = t / C, c = t % C;
  out[t] = acc_g[t] / (se_g[n] + 1e-16f) + b[c];
}

extern "C" void kernel_launch(void* const* d_in, const int* in_sizes, int n_in,
                              void* d_out, int out_size, void* d_ws, size_t ws_size,
                              hipStream_t stream) {
  const int NU = 200000, NB = 50000;
  const float* x_user  = (const float*)d_in[0];
  const float* x_badge = (const float*)d_in[1];
  const int* ub_src = (const int*)d_in[2];
  const int* ub_dst = (const int*)d_in[3];
  const int* bu_src = (const int*)d_in[4];
  const int* bu_dst = (const int*)d_in[5];
  const int nE = in_sizes[2];

  const float* W1_ub_s = (const float*)d_in[8];
  const float* W1_ub_d = (const float*)d_in[9];
  const float* a1_ub_s = (const float*)d_in[10];
  const float* a1_ub_d = (const float*)d_in[11];
  const float* b1_ub   = (const float*)d_in[12];
  const float* W2_ub_s = (const float*)d_in[13];
  const float* W2_ub_d = (const float*)d_in[14];
  const float* a2_ub_s = (const float*)d_in[15];
  const float* a2_ub_d = (const float*)d_in[16];
  const float* b2_ub   = (const float*)d_in[17];
  const float* W1_bu_s = (const float*)d_in[18];
  const float* W1_bu_d = (const float*)d_in[19];
  const float* a1_bu_s = (const float*)d_in[20];
  const float* a1_bu_d = (const float*)d_in[21];
  const float* b1_bu   = (const float*)d_in[22];
  const float* W2_bu_s = (const float*)d_in[23];
  const float* W2_bu_d = (const float*)d_in[24];
  const float* a2_bu_s = (const float*)d_in[25];
  const float* a2_bu_d = (const float*)d_in[26];
  const float* b2_bu   = (const float*)d_in[27];

  const int nbk_ub = (NB + 255) / 256;
  const int nbk_bu = (NU + 1023) / 1024;
  double m_ub = (double)nE * 256.0 / NB;
  double m_bu = (double)nE * 1024.0 / NU;
  int cap_ub = (int)(m_ub + 8.0 * sqrt(m_ub) + 256.0);
  int cap_bu = (int)(m_bu + 8.0 * sqrt(m_bu) + 256.0);

  // ---- workspace carve-up ----
  char* wsb = (char*)d_ws;
  size_t off = 0;
  auto ialloc = [&](size_t n) { int* p = (int*)(wsb + off); off += n * 4; return p; };
  int* rp2_ub  = ialloc((size_t)NB * NS_UB + 1);  // stride-4, sub-sorted by shard
  int* rp_bu   = ialloc(NU + 1);
  int* col_ub  = ialloc(nE);
  int* col_bu  = ialloc(nE);
  int* bcnt_ub = ialloc(256);
  int* bcnt_bu = ialloc(256);
  int* bbase_ub= ialloc(256);
  int* bbase_bu= ialloc(256);
  off = (off + 15) & ~(size_t)15;
  // UNION: part buffer (dead after CSR build) overlays everything below.
  char* pool = wsb + off;
  unsigned long long* part = (unsigned long long*)pool;
  size_t poff = 0;
  auto falloc = [&](size_t n) { float* p = (float*)(pool + poff); poff += n * 4; return p; };
  auto halloc = [&](size_t n) { __half* p = (__half*)(pool + poff); poff += n * 2; return p; };
  __half* hs_u1 = halloc((size_t)NU * 16);
  __half* hs_b1 = halloc((size_t)NB * 16);
  float* hu     = falloc((size_t)NU * 16);
  float* hb     = falloc((size_t)NB * 16);
  float* as_u1  = falloc(NU);
  float* ad_b1  = falloc(NB);
  float* as_b1  = falloc(NB);
  float* ad_u1  = falloc(NU);
  float* hs2_ub = falloc((size_t)NU * 2);
  float* as2_ub = falloc(NU);
  float* ad2_ub = falloc(NB);
  float* hs2_bu = falloc((size_t)NB * 2);
  float* as2_bu = falloc(NB);
  float* ad2_bu = falloc(NU);
  float* acc_ub = falloc((size_t)NB * 16);
  float* se_ub  = falloc(NB);
  (void)ws_size;

  float* ou = (float*)d_out;                   // [NU,2]
  float* ob = (float*)d_out + (size_t)NU * 2;  // [NB,2]

  dim3 blk(256);
  auto g = [](int n) { return dim3((n + 255) / 256); };

  // ===== CSR build =====
  hipMemsetAsync(bcnt_ub, 0, 512 * 4, stream);
  k_partition<<<dim3(NPART_BLOCKS), blk, 0, stream>>>(ub_src, ub_dst, nE, 8, nbk_ub,
                                                      part, cap_ub, bcnt_ub);
  k_scanb<<<dim3(1), blk, 0, stream>>>(bcnt_ub, bbase_ub, nbk_ub);
  k_bucket_csr<256, NS_UB><<<dim3(nbk_ub), blk, 0, stream>>>(
      part, bcnt_ub, bbase_ub, cap_ub, rp2_ub, col_ub, NB, nbk_ub, SHARD_DIV);
  k_partition<<<dim3(NPART_BLOCKS), blk, 0, stream>>>(bu_src, bu_dst, nE, 10, nbk_bu,
                                                      part, cap_bu, bcnt_bu);
  k_scanb<<<dim3(1), blk, 0, stream>>>(bcnt_bu, bbase_bu, nbk_bu);
  k_bucket_csr<1024, 1><<<dim3(nbk_bu), blk, 0, stream>>>(
      part, bcnt_bu, bbase_bu, cap_bu, rp_bu, col_bu, NU, nbk_bu, 1 << 30);

  // ===== layer 1 node transforms (pool writes; part now dead) =====
  k_hs_h<64, 16><<<g(NU), blk, 0, stream>>>(x_user, W1_ub_s, a1_ub_s, hs_u1, as_u1, NU);
  k_ad2<64, false><<<g(NB), blk, 0, stream>>>(x_badge, W1_ub_d, a1_ub_d, ad_b1, NB, 16);
  k_hs_h<64, 16><<<g(NB), blk, 0, stream>>>(x_badge, W1_bu_s, a1_bu_s, hs_b1, as_b1, NB);
  k_ad2<64, false><<<g(NU), blk, 0, stream>>>(x_user, W1_bu_d, a1_bu_d, ad_u1, NU, 16);

  // ===== layer 1 gathers =====
  // ub (dst=badge): 4 src-shards, each hs slice 1.6MB fp16 (L2-resident)
  for (int s = 0; s < NS_UB; ++s)
    k_gpart<16><<<g(NB * 16), blk, 0, stream>>>(rp2_ub, col_ub, as_u1, ad_b1, hs_u1,
                                                acc_ub, se_ub, NB, s, s == 0 ? 1 : 0);
  k_gfin<16><<<g(NB * 16), blk, 0, stream>>>(acc_ub, se_ub, b1_ub, hb, NB);
  // bu (dst=user): fp16 table 1.6MB, single pass
  k_gather<16, 1, __half><<<g(NU * 16), blk, 0, stream>>>(rp_bu, 1, col_bu, as_b1, ad_u1,
                                                          hs_b1, b1_bu, hu, NU);

  // ===== layer 2 node transforms (relu folded) =====
  k_hs<16, 2, true><<<g(NU), blk, 0, stream>>>(hu, W2_ub_s, a2_ub_s, hs2_ub, as2_ub, NU);
  k_ad2<16, true><<<g(NB), blk, 0, stream>>>(hb, W2_ub_d, a2_ub_d, ad2_ub, NB, 2);
  k_hs<16, 2, true><<<g(NB), blk, 0, stream>>>(hb, W2_bu_s, a2_bu_s, hs2_bu, as2_bu, NB);
  k_ad2<16, true><<<g(NU), blk, 0, stream>>>(hu, W2_bu_d, a2_bu_d, ad2_bu, NU, 2);

  // ===== layer 2 gathers (fp32 hs2, tiny tables) =====
  k_gather<2, 4, float><<<g(NB * 8), blk, 0, stream>>>(rp2_ub, NS_UB, col_ub, as2_ub,
                                                       ad2_ub, hs2_ub, b2_ub, ob, NB);
  k_gather<2, 4, float><<<g(NU * 8), blk, 0, stream>>>(rp_bu, 1, col_bu, as2_bu,
                                                       ad2_bu, hs2_bu, b2_bu, ou, NU);
}

// Round 6
// 898.364 us; speedup vs baseline: 11.7818x; 1.1169x over previous
//
#include <hip/hip_runtime.h>
#include <hip/hip_fp16.h>
#include <math.h>

// HeteroGNN: 2-layer bipartite single-head GAT (users<->badges).
// R6: attack k_partition (120us each, WRITE 135MB vs 40MB ideal = scattered
// 8B partial-line stores):
//   - block-level LDS counting sort, COALESCED full-line flush to part
//   - part packed u32: (dst_local<<18)|src  (traffic halved, 40->20MB)
//   - bucket_csr unified (runtime npb/ns), reads u32 part
//   - dense node passes fused: each of x_user/x_badge/hu/hb read ONCE
//     (hs + alpha_s + other-relation alpha_d in one kernel)
// Gathers (fp16 hs, ub src-sharded) unchanged from R5.

#define NEG_SLOPE 0.2f
#define NS_UB 4
#define SHARD_DIV 50000
#define PART_PER 4880  // max edges per partition block (LDS sort buffer)

__device__ __forceinline__ float lrelu(float x) { return x > 0.f ? x : NEG_SLOPE * x; }

// ---------------- fused dense node kernel ----------------
// hs[n,:] = (relu?)x[n,:] @ Ws ; alpha_s[n] = hs[n,:] @ a_s ;
// alpha_d[n] = (relu?)x[n,:] @ (Wd_o @ a_d_o)   (for the other relation)
template <int F, int C, bool RELU_IN, typename HT>
__global__ void k_nodes(const float* __restrict__ x, const float* __restrict__ Ws,
                        const float* __restrict__ a_s, const float* __restrict__ Wd_o,
                        const float* __restrict__ a_d_o, HT* __restrict__ hs,
                        float* __restrict__ alpha_s, float* __restrict__ alpha_d, int N) {
  __shared__ float sW[F * C];
  __shared__ float sa[C];
  __shared__ float sv[F];
  for (int i = threadIdx.x; i < F * C; i += blockDim.x) sW[i] = Ws[i];
  if (threadIdx.x < C) sa[threadIdx.x] = a_s[threadIdx.x];
  if (threadIdx.x < F) {
    float s = 0.f;
    for (int c = 0; c < C; ++c) s += Wd_o[threadIdx.x * C + c] * a_d_o[c];
    sv[threadIdx.x] = s;
  }
  __syncthreads();
  int n = blockIdx.x * blockDim.x + threadIdx.x;
  if (n >= N) return;
  float acc[C];
#pragma unroll
  for (int c = 0; c < C; ++c) acc[c] = 0.f;
  float ad = 0.f;
  const float* xr = x + (size_t)n * F;
#pragma unroll 4
  for (int f = 0; f < F; ++f) {
    float xv = xr[f];
    if (RELU_IN) xv = fmaxf(xv, 0.f);
#pragma unroll
    for (int c = 0; c < C; ++c) acc[c] += xv * sW[f * C + c];
    ad += xv * sv[f];
  }
  float al = 0.f;
#pragma unroll
  for (int c = 0; c < C; ++c) {
    hs[(size_t)n * C + c] = (HT)acc[c];
    al += acc[c] * sa[c];
  }
  alpha_s[n] = al;
  alpha_d[n] = ad;
}

// ---------------- CSR build ----------------

// pass 1: block-local LDS counting sort by coarse bucket (dst>>shift),
// coalesced u32 flush: part value = (dst_local << 18) | src.
__global__ void k_partition(const int* __restrict__ src, const int* __restrict__ dst,
                            int nE, int shift, int mask, int nbuck,
                            unsigned* __restrict__ part, int cap,
                            int* __restrict__ bcnt) {
  __shared__ unsigned s_sorted[PART_PER];
  __shared__ int h[257];    // runstart bounds
  __shared__ int ps[256];
  __shared__ int resb[256];
  __shared__ int cur[256];
  int per = (nE + gridDim.x - 1) / gridDim.x;
  int beg = blockIdx.x * per;
  int end = min(beg + per, nE);
  int cnt = end - beg;
  int t = threadIdx.x;
  h[t] = 0;
  __syncthreads();
  for (int i = beg + t; i < end; i += 256) atomicAdd(&h[dst[i] >> shift], 1);
  __syncthreads();
  int v = h[t];
  ps[t] = v;
  __syncthreads();
  for (int off = 1; off < 256; off <<= 1) {
    int u = (t >= off) ? ps[t - off] : 0;
    __syncthreads();
    ps[t] += u;
    __syncthreads();
  }
  int excl = ps[t] - v;
  resb[t] = (t < nbuck && v > 0) ? atomicAdd(&bcnt[t], v) : 0;  // aggregated
  __syncthreads();
  h[t] = excl;
  cur[t] = excl;
  if (t == 255) h[256] = excl + v;
  __syncthreads();
  // scatter into sorted LDS
  for (int i = beg + t; i < end; i += 256) {
    int d = dst[i];
    int b = d >> shift;
    int r = atomicAdd(&cur[b], 1);
    s_sorted[r] = ((unsigned)(d & mask) << 18) | (unsigned)src[i];
  }
  __syncthreads();
  // coalesced flush: consecutive i -> consecutive global within a bucket run
  for (int i = t; i < cnt; i += 256) {
    int lo = 0, hi = 256;  // find b: h[b] <= i < h[b+1]
    while (hi - lo > 1) {
      int mid = (lo + hi) >> 1;
      if (h[mid] <= i) lo = mid; else hi = mid;
    }
    int p = resb[lo] + (i - h[lo]);
    if (p < cap) part[(size_t)lo * cap + p] = s_sorted[i];
  }
}

__global__ void k_scanb(const int* __restrict__ bcnt, int* __restrict__ bbase, int nbuck) {
  __shared__ int lds[256];
  int t = threadIdx.x;
  int v = (t < nbuck) ? bcnt[t] : 0;
  lds[t] = v;
  __syncthreads();
  for (int off = 1; off < 256; off <<= 1) {
    int u = (t >= off) ? lds[t - off] : 0;
    __syncthreads();
    lds[t] += u;
    __syncthreads();
  }
  if (t < nbuck) bbase[t] = lds[t] - v;
}

// pass 2: one block per bucket -> rp2 (stride ns, sub-sorted by src shard) + col
// npb*ns == 1024 for both configs.
__global__ void k_bucket_csr(const unsigned* __restrict__ part,
                             const int* __restrict__ bcnt, const int* __restrict__ bbase,
                             int cap, int* __restrict__ rp2, int* __restrict__ col,
                             int N, int nbuck, int npb, int ns, int sdiv) {
  __shared__ int hist[1024];
  __shared__ int start[1024];
  __shared__ int ps[256];
  int b = blockIdx.x;
  int t = threadIdx.x;
  int node0 = b * npb;
  int cnt = min(bcnt[b], cap);
  int base = bbase[b];
  const unsigned* pp = part + (size_t)b * cap;
  for (int i = t; i < 1024; i += 256) hist[i] = 0;
  __syncthreads();
  for (int i = t; i < cnt; i += 256) {
    unsigned e = pp[i];
    int dl = (int)(e >> 18);
    int sv = (int)(e & 0x3FFFFu);
    int bin = dl * ns + ((ns == 1) ? 0 : sv / sdiv);
    atomicAdd(&hist[bin], 1);
  }
  __syncthreads();
  int tp[4];
  int sum = 0;
#pragma unroll
  for (int k = 0; k < 4; ++k) { tp[k] = sum; sum += hist[t * 4 + k]; }
  ps[t] = sum;
  __syncthreads();
  for (int off = 1; off < 256; off <<= 1) {
    int u = (t >= off) ? ps[t - off] : 0;
    __syncthreads();
    ps[t] += u;
    __syncthreads();
  }
  int te = ps[t] - sum;
#pragma unroll
  for (int k = 0; k < 4; ++k) start[t * 4 + k] = te + tp[k];
  __syncthreads();
  for (int i = t; i < 1024; i += 256) {
    int node = node0 + i / ns;
    if (node < N) rp2[(size_t)node0 * ns + i] = base + start[i];
  }
  if (b == nbuck - 1 && t == 0) rp2[(size_t)N * ns] = base + cnt;
  __syncthreads();
  for (int i = t; i < cnt; i += 256) {
    unsigned e = pp[i];
    int dl = (int)(e >> 18);
    int sv = (int)(e & 0x3FFFFu);
    int bin = dl * ns + ((ns == 1) ? 0 : sv / sdiv);
    int r = atomicAdd(&start[bin], 1);
    col[base + r] = sv;
  }
}

// ---------------- gathers ----------------

template <int C, int ESPLIT, typename HT>
__global__ void k_gather(const int* __restrict__ rp, int rs, const int* __restrict__ col,
                         const float* __restrict__ as, const float* __restrict__ ad,
                         const HT* __restrict__ hs, const float* __restrict__ b,
                         float* __restrict__ out, int N) {
  constexpr int GROUP = C * ESPLIT;
  int t = blockIdx.x * blockDim.x + threadIdx.x;
  int n = t / GROUP;
  if (n >= N) return;
  int lane = t % GROUP;
  int c = lane % C;
  int j = lane / C;
  int beg = rp[(size_t)n * rs], end = rp[(size_t)(n + 1) * rs];
  float adv = ad[n];
  float acc = 0.f, se = 0.f;
  for (int k = beg + j; k < end; k += ESPLIT) {
    int s = col[k];
    float w = __expf(lrelu(as[s] + adv));
    se += w;
    acc += w * (float)hs[(size_t)s * C + c];
  }
#pragma unroll
  for (int m = C; m < GROUP; m <<= 1) {
    acc += __shfl_xor(acc, m, GROUP);
    se += __shfl_xor(se, m, GROUP);
  }
  if (j == 0) out[(size_t)n * C + c] = acc / (se + 1e-16f) + b[c];
}

template <int C>
__global__ void k_gpart(const int* __restrict__ rp2, const int* __restrict__ col,
                        const float* __restrict__ as, const float* __restrict__ ad,
                        const __half* __restrict__ hs, float* __restrict__ acc_g,
                        float* __restrict__ se_g, int N, int s, int first) {
  int t = blockIdx.x * blockDim.x + threadIdx.x;
  int n = t / C;
  if (n >= N) return;
  int c = t % C;
  int beg = rp2[(size_t)n * NS_UB + s], end = rp2[(size_t)n * NS_UB + s + 1];
  float adv = ad[n];
  float acc = 0.f, se = 0.f;
  for (int k = beg; k < end; ++k) {
    int sv = col[k];
    float w = __expf(lrelu(as[sv] + adv));
    se += w;
    acc += w * (float)hs[(size_t)sv * C + c];
  }
  size_t oi = (size_t)n * C + c;
  if (first) {
    acc_g[oi] = acc;
    if (c == 0) se_g[n] = se;
  } else {
    acc_g[oi] += acc;
    if (c == 0) se_g[n] += se;
  }
}

template <int C>
__global__ void k_gfin(const float* __restrict__ acc_g, const float* __restrict__ se_g,
                       const float* __restrict__ b, float* __restrict__ out, int N) {
  int t = blockIdx.x * blockDim.x + threadIdx.x;
  if (t >= N * C) return;
  int n = t / C, c = t % C;
  out[t] = acc_g[t] / (se_g[n] + 1e-16f) + b[c];
}

extern "C" void kernel_launch(void* const* d_in, const int* in_sizes, int n_in,
                              void* d_out, int out_size, void* d_ws, size_t ws_size,
                              hipStream_t stream) {
  const int NU = 200000, NB = 50000;
  const float* x_user  = (const float*)d_in[0];
  const float* x_badge = (const float*)d_in[1];
  const int* ub_src = (const int*)d_in[2];
  const int* ub_dst = (const int*)d_in[3];
  const int* bu_src = (const int*)d_in[4];
  const int* bu_dst = (const int*)d_in[5];
  const int nE = in_sizes[2];

  const float* W1_ub_s = (const float*)d_in[8];
  const float* W1_ub_d = (const float*)d_in[9];
  const float* a1_ub_s = (const float*)d_in[10];
  const float* a1_ub_d = (const float*)d_in[11];
  const float* b1_ub   = (const float*)d_in[12];
  const float* W2_ub_s = (const float*)d_in[13];
  const float* W2_ub_d = (const float*)d_in[14];
  const float* a2_ub_s = (const float*)d_in[15];
  const float* a2_ub_d = (const float*)d_in[16];
  const float* b2_ub   = (const float*)d_in[17];
  const float* W1_bu_s = (const float*)d_in[18];
  const float* W1_bu_d = (const float*)d_in[19];
  const float* a1_bu_s = (const float*)d_in[20];
  const float* a1_bu_d = (const float*)d_in[21];
  const float* b1_bu   = (const float*)d_in[22];
  const float* W2_bu_s = (const float*)d_in[23];
  const float* W2_bu_d = (const float*)d_in[24];
  const float* a2_bu_s = (const float*)d_in[25];
  const float* a2_bu_d = (const float*)d_in[26];
  const float* b2_bu   = (const float*)d_in[27];

  const int nbk_ub = (NB + 255) / 256;      // 196
  const int nbk_bu = (NU + 1023) / 1024;    // 196
  double m_ub = (double)nE * 256.0 / NB;
  double m_bu = (double)nE * 1024.0 / NU;
  int cap_ub = (int)(m_ub + 8.0 * sqrt(m_ub) + 256.0);
  int cap_bu = (int)(m_bu + 8.0 * sqrt(m_bu) + 256.0);
  const int pblocks = (nE + PART_PER - 1) / PART_PER;  // per <= PART_PER

  // ---- workspace carve-up ----
  char* wsb = (char*)d_ws;
  size_t off = 0;
  auto ialloc = [&](size_t n) { int* p = (int*)(wsb + off); off += n * 4; return p; };
  int* rp2_ub  = ialloc((size_t)NB * NS_UB + 1);
  int* rp_bu   = ialloc(NU + 1);
  int* col_ub  = ialloc(nE);
  int* col_bu  = ialloc(nE);
  int* bcnt_ub = ialloc(256);
  int* bcnt_bu = ialloc(256);
  int* bbase_ub= ialloc(256);
  int* bbase_bu= ialloc(256);
  off = (off + 15) & ~(size_t)15;
  // UNION: u32 part buffer (dead after each bucket pass) overlays the pool.
  char* pool = wsb + off;
  unsigned* part = (unsigned*)pool;
  size_t poff = 0;
  auto falloc = [&](size_t n) { float* p = (float*)(pool + poff); poff += n * 4; return p; };
  auto halloc = [&](size_t n) { __half* p = (__half*)(pool + poff); poff += n * 2; return p; };
  __half* hs_u1 = halloc((size_t)NU * 16);
  __half* hs_b1 = halloc((size_t)NB * 16);
  float* hu     = falloc((size_t)NU * 16);
  float* hb     = falloc((size_t)NB * 16);
  float* as_u1  = falloc(NU);
  float* ad_b1  = falloc(NB);
  float* as_b1  = falloc(NB);
  float* ad_u1  = falloc(NU);
  float* hs2_ub = falloc((size_t)NU * 2);
  float* as2_ub = falloc(NU);
  float* ad2_ub = falloc(NB);
  float* hs2_bu = falloc((size_t)NB * 2);
  float* as2_bu = falloc(NB);
  float* ad2_bu = falloc(NU);
  float* acc_ub = falloc((size_t)NB * 16);
  float* se_ub  = falloc(NB);
  (void)ws_size;

  float* ou = (float*)d_out;                   // [NU,2]
  float* ob = (float*)d_out + (size_t)NU * 2;  // [NB,2]

  dim3 blk(256);
  auto g = [](int n) { return dim3((n + 255) / 256); };

  // ===== CSR build (sequential per graph; part buffer reused) =====
  hipMemsetAsync(bcnt_ub, 0, 512 * 4, stream);
  k_partition<<<dim3(pblocks), blk, 0, stream>>>(ub_src, ub_dst, nE, 8, 255, nbk_ub,
                                                 part, cap_ub, bcnt_ub);
  k_scanb<<<dim3(1), blk, 0, stream>>>(bcnt_ub, bbase_ub, nbk_ub);
  k_bucket_csr<<<dim3(nbk_ub), blk, 0, stream>>>(part, bcnt_ub, bbase_ub, cap_ub,
                                                 rp2_ub, col_ub, NB, nbk_ub,
                                                 256, NS_UB, SHARD_DIV);
  k_partition<<<dim3(pblocks), blk, 0, stream>>>(bu_src, bu_dst, nE, 10, 1023, nbk_bu,
                                                 part, cap_bu, bcnt_bu);
  k_scanb<<<dim3(1), blk, 0, stream>>>(bcnt_bu, bbase_bu, nbk_bu);
  k_bucket_csr<<<dim3(nbk_bu), blk, 0, stream>>>(part, bcnt_bu, bbase_bu, cap_bu,
                                                 rp_bu, col_bu, NU, nbk_bu,
                                                 1024, 1, 1 << 30);

  // ===== layer 1 node transforms (fused; each x read once; part now dead) =====
  k_nodes<64, 16, false, __half><<<g(NU), blk, 0, stream>>>(
      x_user, W1_ub_s, a1_ub_s, W1_bu_d, a1_bu_d, hs_u1, as_u1, ad_u1, NU);
  k_nodes<64, 16, false, __half><<<g(NB), blk, 0, stream>>>(
      x_badge, W1_bu_s, a1_bu_s, W1_ub_d, a1_ub_d, hs_b1, as_b1, ad_b1, NB);

  // ===== layer 1 gathers =====
  for (int s = 0; s < NS_UB; ++s)
    k_gpart<16><<<g(NB * 16), blk, 0, stream>>>(rp2_ub, col_ub, as_u1, ad_b1, hs_u1,
                                                acc_ub, se_ub, NB, s, s == 0 ? 1 : 0);
  k_gfin<16><<<g(NB * 16), blk, 0, stream>>>(acc_ub, se_ub, b1_ub, hb, NB);
  k_gather<16, 1, __half><<<g(NU * 16), blk, 0, stream>>>(rp_bu, 1, col_bu, as_b1, ad_u1,
                                                          hs_b1, b1_bu, hu, NU);

  // ===== layer 2 node transforms (fused, relu folded) =====
  k_nodes<16, 2, true, float><<<g(NU), blk, 0, stream>>>(
      hu, W2_ub_s, a2_ub_s, W2_bu_d, a2_bu_d, hs2_ub, as2_ub, ad2_bu, NU);
  k_nodes<16, 2, true, float><<<g(NB), blk, 0, stream>>>(
      hb, W2_bu_s, a2_bu_s, W2_ub_d, a2_ub_d, hs2_bu, as2_bu, ad2_ub, NB);

  // ===== layer 2 gathers =====
  k_gather<2, 4, float><<<g(NB * 8), blk, 0, stream>>>(rp2_ub, NS_UB, col_ub, as2_ub,
                                                       ad2_ub, hs2_ub, b2_ub, ob, NB);
  k_gather<2, 4, float><<<g(NU * 8), blk, 0, stream>>>(rp_bu, 1, col_bu, as2_bu,
                                                       ad2_bu, hs2_bu, b2_bu, ou, NU);
}

// Round 7
// 787.656 us; speedup vs baseline: 13.4377x; 1.1406x over previous
//
#include <hip/hip_runtime.h>
#include <hip/hip_fp16.h>
#include <math.h>

// HeteroGNN: 2-layer bipartite single-head GAT (users<->badges).
// R7: gathers rebuilt "lane-owned edges" (R6 counters: bu-L1 gather 92us,
// VALUBusy 48%, HBM 4.6% -> VALU-redundancy bound; GROUP=16 lanes were
// recomputing expf/col/as 16x per edge). Now each lane owns whole edges:
// 1 expf + 1 col + 1 as + vectorized hs-row load per edge; xor-butterfly
// (width 16) reduces acc[C]+se; lane 0 writes the row.
// CSR build (LDS counting sort, u32 part) and fused node kernels unchanged.

#define NEG_SLOPE 0.2f
#define NS_UB 4
#define SHARD_DIV 50000
#define PART_PER 4880  // max edges per partition block (LDS sort buffer)

__device__ __forceinline__ float lrelu(float x) { return x > 0.f ? x : NEG_SLOPE * x; }

// ---------------- fused dense node kernel ----------------
template <int F, int C, bool RELU_IN, typename HT>
__global__ void k_nodes(const float* __restrict__ x, const float* __restrict__ Ws,
                        const float* __restrict__ a_s, const float* __restrict__ Wd_o,
                        const float* __restrict__ a_d_o, HT* __restrict__ hs,
                        float* __restrict__ alpha_s, float* __restrict__ alpha_d, int N) {
  __shared__ float sW[F * C];
  __shared__ float sa[C];
  __shared__ float sv[F];
  for (int i = threadIdx.x; i < F * C; i += blockDim.x) sW[i] = Ws[i];
  if (threadIdx.x < C) sa[threadIdx.x] = a_s[threadIdx.x];
  if (threadIdx.x < F) {
    float s = 0.f;
    for (int c = 0; c < C; ++c) s += Wd_o[threadIdx.x * C + c] * a_d_o[c];
    sv[threadIdx.x] = s;
  }
  __syncthreads();
  int n = blockIdx.x * blockDim.x + threadIdx.x;
  if (n >= N) return;
  float acc[C];
#pragma unroll
  for (int c = 0; c < C; ++c) acc[c] = 0.f;
  float ad = 0.f;
  const float* xr = x + (size_t)n * F;
#pragma unroll 4
  for (int f = 0; f < F; ++f) {
    float xv = xr[f];
    if (RELU_IN) xv = fmaxf(xv, 0.f);
#pragma unroll
    for (int c = 0; c < C; ++c) acc[c] += xv * sW[f * C + c];
    ad += xv * sv[f];
  }
  float al = 0.f;
#pragma unroll
  for (int c = 0; c < C; ++c) {
    hs[(size_t)n * C + c] = (HT)acc[c];
    al += acc[c] * sa[c];
  }
  alpha_s[n] = al;
  alpha_d[n] = ad;
}

// ---------------- CSR build ----------------

__global__ void k_partition(const int* __restrict__ src, const int* __restrict__ dst,
                            int nE, int shift, int mask, int nbuck,
                            unsigned* __restrict__ part, int cap,
                            int* __restrict__ bcnt) {
  __shared__ unsigned s_sorted[PART_PER];
  __shared__ int h[257];
  __shared__ int ps[256];
  __shared__ int resb[256];
  __shared__ int cur[256];
  int per = (nE + gridDim.x - 1) / gridDim.x;
  int beg = blockIdx.x * per;
  int end = min(beg + per, nE);
  int cnt = end - beg;
  int t = threadIdx.x;
  h[t] = 0;
  __syncthreads();
  for (int i = beg + t; i < end; i += 256) atomicAdd(&h[dst[i] >> shift], 1);
  __syncthreads();
  int v = h[t];
  ps[t] = v;
  __syncthreads();
  for (int off = 1; off < 256; off <<= 1) {
    int u = (t >= off) ? ps[t - off] : 0;
    __syncthreads();
    ps[t] += u;
    __syncthreads();
  }
  int excl = ps[t] - v;
  resb[t] = (t < nbuck && v > 0) ? atomicAdd(&bcnt[t], v) : 0;
  __syncthreads();
  h[t] = excl;
  cur[t] = excl;
  if (t == 255) h[256] = excl + v;
  __syncthreads();
  for (int i = beg + t; i < end; i += 256) {
    int d = dst[i];
    int b = d >> shift;
    int r = atomicAdd(&cur[b], 1);
    s_sorted[r] = ((unsigned)(d & mask) << 18) | (unsigned)src[i];
  }
  __syncthreads();
  for (int i = t; i < cnt; i += 256) {
    int lo = 0, hi = 256;
    while (hi - lo > 1) {
      int mid = (lo + hi) >> 1;
      if (h[mid] <= i) lo = mid; else hi = mid;
    }
    int p = resb[lo] + (i - h[lo]);
    if (p < cap) part[(size_t)lo * cap + p] = s_sorted[i];
  }
}

__global__ void k_scanb(const int* __restrict__ bcnt, int* __restrict__ bbase, int nbuck) {
  __shared__ int lds[256];
  int t = threadIdx.x;
  int v = (t < nbuck) ? bcnt[t] : 0;
  lds[t] = v;
  __syncthreads();
  for (int off = 1; off < 256; off <<= 1) {
    int u = (t >= off) ? lds[t - off] : 0;
    __syncthreads();
    lds[t] += u;
    __syncthreads();
  }
  if (t < nbuck) bbase[t] = lds[t] - v;
}

__global__ void k_bucket_csr(const unsigned* __restrict__ part,
                             const int* __restrict__ bcnt, const int* __restrict__ bbase,
                             int cap, int* __restrict__ rp2, int* __restrict__ col,
                             int N, int nbuck, int npb, int ns, int sdiv) {
  __shared__ int hist[1024];
  __shared__ int start[1024];
  __shared__ int ps[256];
  int b = blockIdx.x;
  int t = threadIdx.x;
  int node0 = b * npb;
  int cnt = min(bcnt[b], cap);
  int base = bbase[b];
  const unsigned* pp = part + (size_t)b * cap;
  for (int i = t; i < 1024; i += 256) hist[i] = 0;
  __syncthreads();
  for (int i = t; i < cnt; i += 256) {
    unsigned e = pp[i];
    int dl = (int)(e >> 18);
    int sv = (int)(e & 0x3FFFFu);
    int bin = dl * ns + ((ns == 1) ? 0 : sv / sdiv);
    atomicAdd(&hist[bin], 1);
  }
  __syncthreads();
  int tp[4];
  int sum = 0;
#pragma unroll
  for (int k = 0; k < 4; ++k) { tp[k] = sum; sum += hist[t * 4 + k]; }
  ps[t] = sum;
  __syncthreads();
  for (int off = 1; off < 256; off <<= 1) {
    int u = (t >= off) ? ps[t - off] : 0;
    __syncthreads();
    ps[t] += u;
    __syncthreads();
  }
  int te = ps[t] - sum;
#pragma unroll
  for (int k = 0; k < 4; ++k) start[t * 4 + k] = te + tp[k];
  __syncthreads();
  for (int i = t; i < 1024; i += 256) {
    int node = node0 + i / ns;
    if (node < N) rp2[(size_t)node0 * ns + i] = base + start[i];
  }
  if (b == nbuck - 1 && t == 0) rp2[(size_t)N * ns] = base + cnt;
  __syncthreads();
  for (int i = t; i < cnt; i += 256) {
    unsigned e = pp[i];
    int dl = (int)(e >> 18);
    int sv = (int)(e & 0x3FFFFu);
    int bin = dl * ns + ((ns == 1) ? 0 : sv / sdiv);
    int r = atomicAdd(&start[bin], 1);
    col[base + r] = sv;
  }
}

// ---------------- gathers: lane-owned edges, GROUP=16 ----------------

template <int C, typename HT>
__device__ __forceinline__ void load_row(const HT* __restrict__ hs, int s, float (&row)[C]) {
  if constexpr (sizeof(HT) == 2 && C == 16) {
    union { uint4 v[2]; __half h[16]; } buf;
    const uint4* hv = (const uint4*)(hs + (size_t)s * 16);
    buf.v[0] = hv[0];
    buf.v[1] = hv[1];
#pragma unroll
    for (int c = 0; c < 16; ++c) row[c] = __half2float(buf.h[c]);
  } else if constexpr (sizeof(HT) == 4 && C == 2) {
    float2 v = *(const float2*)((const float*)hs + (size_t)s * 2);
    row[0] = v.x;
    row[1] = v.y;
  } else {
#pragma unroll
    for (int c = 0; c < C; ++c) row[c] = (float)hs[(size_t)s * C + c];
  }
}

// full fused gather (softmax + aggregate + bias); rp indexed with stride rs
template <int C, typename HT>
__global__ void k_gather16(const int* __restrict__ rp, int rs, const int* __restrict__ col,
                           const float* __restrict__ as, const float* __restrict__ ad,
                           const HT* __restrict__ hs, const float* __restrict__ b,
                           float* __restrict__ out, int N) {
  int t = blockIdx.x * blockDim.x + threadIdx.x;
  int n = t >> 4;
  if (n >= N) return;
  int j = t & 15;
  int beg = rp[(size_t)n * rs], end = rp[(size_t)(n + 1) * rs];
  float adv = ad[n];
  float acc[C];
#pragma unroll
  for (int c = 0; c < C; ++c) acc[c] = 0.f;
  float se = 0.f;
  for (int k = beg + j; k < end; k += 16) {
    int s = col[k];
    float w = __expf(lrelu(as[s] + adv));
    se += w;
    float row[C];
    load_row<C, HT>(hs, s, row);
#pragma unroll
    for (int c = 0; c < C; ++c) acc[c] += w * row[c];
  }
#pragma unroll
  for (int m = 1; m < 16; m <<= 1) {
    se += __shfl_xor(se, m, 16);
#pragma unroll
    for (int c = 0; c < C; ++c) acc[c] += __shfl_xor(acc[c], m, 16);
  }
  if (j == 0) {
    float inv = 1.f / (se + 1e-16f);
#pragma unroll
    for (int c = 0; c < C; ++c) out[(size_t)n * C + c] = acc[c] * inv + b[c];
  }
}

// sharded partial gather (ub layer 1): shard s of NS_UB; dst-owned RMW
template <int C>
__global__ void k_gpart16(const int* __restrict__ rp2, const int* __restrict__ col,
                          const float* __restrict__ as, const float* __restrict__ ad,
                          const __half* __restrict__ hs, float* __restrict__ acc_g,
                          float* __restrict__ se_g, int N, int s, int first) {
  int t = blockIdx.x * blockDim.x + threadIdx.x;
  int n = t >> 4;
  if (n >= N) return;
  int j = t & 15;
  int beg = rp2[(size_t)n * NS_UB + s], end = rp2[(size_t)n * NS_UB + s + 1];
  float adv = ad[n];
  float acc[C];
#pragma unroll
  for (int c = 0; c < C; ++c) acc[c] = 0.f;
  float se = 0.f;
  for (int k = beg + j; k < end; k += 16) {
    int sv = col[k];
    float w = __expf(lrelu(as[sv] + adv));
    se += w;
    float row[C];
    load_row<C, __half>(hs, sv, row);
#pragma unroll
    for (int c = 0; c < C; ++c) acc[c] += w * row[c];
  }
#pragma unroll
  for (int m = 1; m < 16; m <<= 1) {
    se += __shfl_xor(se, m, 16);
#pragma unroll
    for (int c = 0; c < C; ++c) acc[c] += __shfl_xor(acc[c], m, 16);
  }
  if (j == 0) {
    float* o = acc_g + (size_t)n * C;
    if (first) {
#pragma unroll
      for (int c = 0; c < C; ++c) o[c] = acc[c];
      se_g[n] = se;
    } else {
#pragma unroll
      for (int c = 0; c < C; ++c) o[c] += acc[c];
      se_g[n] += se;
    }
  }
}

template <int C>
__global__ void k_gfin(const float* __restrict__ acc_g, const float* __restrict__ se_g,
                       const float* __restrict__ b, float* __restrict__ out, int N) {
  int t = blockIdx.x * blockDim.x + threadIdx.x;
  if (t >= N * C) return;
  int n = t / C, c = t % C;
  out[t] = acc_g[t] / (se_g[n] + 1e-16f) + b[c];
}

extern "C" void kernel_launch(void* const* d_in, const int* in_sizes, int n_in,
                              void* d_out, int out_size, void* d_ws, size_t ws_size,
                              hipStream_t stream) {
  const int NU = 200000, NB = 50000;
  const float* x_user  = (const float*)d_in[0];
  const float* x_badge = (const float*)d_in[1];
  const int* ub_src = (const int*)d_in[2];
  const int* ub_dst = (const int*)d_in[3];
  const int* bu_src = (const int*)d_in[4];
  const int* bu_dst = (const int*)d_in[5];
  const int nE = in_sizes[2];

  const float* W1_ub_s = (const float*)d_in[8];
  const float* W1_ub_d = (const float*)d_in[9];
  const float* a1_ub_s = (const float*)d_in[10];
  const float* a1_ub_d = (const float*)d_in[11];
  const float* b1_ub   = (const float*)d_in[12];
  const float* W2_ub_s = (const float*)d_in[13];
  const float* W2_ub_d = (const float*)d_in[14];
  const float* a2_ub_s = (const float*)d_in[15];
  const float* a2_ub_d = (const float*)d_in[16];
  const float* b2_ub   = (const float*)d_in[17];
  const float* W1_bu_s = (const float*)d_in[18];
  const float* W1_bu_d = (const float*)d_in[19];
  const float* a1_bu_s = (const float*)d_in[20];
  const float* a1_bu_d = (const float*)d_in[21];
  const float* b1_bu   = (const float*)d_in[22];
  const float* W2_bu_s = (const float*)d_in[23];
  const float* W2_bu_d = (const float*)d_in[24];
  const float* a2_bu_s = (const float*)d_in[25];
  const float* a2_bu_d = (const float*)d_in[26];
  const float* b2_bu   = (const float*)d_in[27];

  const int nbk_ub = (NB + 255) / 256;      // 196
  const int nbk_bu = (NU + 1023) / 1024;    // 196
  double m_ub = (double)nE * 256.0 / NB;
  double m_bu = (double)nE * 1024.0 / NU;
  int cap_ub = (int)(m_ub + 8.0 * sqrt(m_ub) + 256.0);
  int cap_bu = (int)(m_bu + 8.0 * sqrt(m_bu) + 256.0);
  const int pblocks = (nE + PART_PER - 1) / PART_PER;

  // ---- workspace carve-up ----
  char* wsb = (char*)d_ws;
  size_t off = 0;
  auto ialloc = [&](size_t n) { int* p = (int*)(wsb + off); off += n * 4; return p; };
  int* rp2_ub  = ialloc((size_t)NB * NS_UB + 1);
  int* rp_bu   = ialloc(NU + 1);
  int* col_ub  = ialloc(nE);
  int* col_bu  = ialloc(nE);
  int* bcnt_ub = ialloc(256);
  int* bcnt_bu = ialloc(256);
  int* bbase_ub= ialloc(256);
  int* bbase_bu= ialloc(256);
  off = (off + 15) & ~(size_t)15;
  // UNION: u32 part buffer (dead after each bucket pass) overlays the pool.
  char* pool = wsb + off;
  unsigned* part = (unsigned*)pool;
  size_t poff = 0;
  auto falloc = [&](size_t n) { float* p = (float*)(pool + poff); poff += n * 4; return p; };
  auto halloc = [&](size_t n) { __half* p = (__half*)(pool + poff); poff += n * 2; return p; };
  __half* hs_u1 = halloc((size_t)NU * 16);
  __half* hs_b1 = halloc((size_t)NB * 16);
  float* hu     = falloc((size_t)NU * 16);
  float* hb     = falloc((size_t)NB * 16);
  float* as_u1  = falloc(NU);
  float* ad_b1  = falloc(NB);
  float* as_b1  = falloc(NB);
  float* ad_u1  = falloc(NU);
  float* hs2_ub = falloc((size_t)NU * 2);
  float* as2_ub = falloc(NU);
  float* ad2_ub = falloc(NB);
  float* hs2_bu = falloc((size_t)NB * 2);
  float* as2_bu = falloc(NB);
  float* ad2_bu = falloc(NU);
  float* acc_ub = falloc((size_t)NB * 16);
  float* se_ub  = falloc(NB);
  (void)ws_size;

  float* ou = (float*)d_out;                   // [NU,2]
  float* ob = (float*)d_out + (size_t)NU * 2;  // [NB,2]

  dim3 blk(256);
  auto g = [](int n) { return dim3((n + 255) / 256); };

  // ===== CSR build (sequential per graph; part buffer reused) =====
  hipMemsetAsync(bcnt_ub, 0, 512 * 4, stream);
  k_partition<<<dim3(pblocks), blk, 0, stream>>>(ub_src, ub_dst, nE, 8, 255, nbk_ub,
                                                 part, cap_ub, bcnt_ub);
  k_scanb<<<dim3(1), blk, 0, stream>>>(bcnt_ub, bbase_ub, nbk_ub);
  k_bucket_csr<<<dim3(nbk_ub), blk, 0, stream>>>(part, bcnt_ub, bbase_ub, cap_ub,
                                                 rp2_ub, col_ub, NB, nbk_ub,
                                                 256, NS_UB, SHARD_DIV);
  k_partition<<<dim3(pblocks), blk, 0, stream>>>(bu_src, bu_dst, nE, 10, 1023, nbk_bu,
                                                 part, cap_bu, bcnt_bu);
  k_scanb<<<dim3(1), blk, 0, stream>>>(bcnt_bu, bbase_bu, nbk_bu);
  k_bucket_csr<<<dim3(nbk_bu), blk, 0, stream>>>(part, bcnt_bu, bbase_bu, cap_bu,
                                                 rp_bu, col_bu, NU, nbk_bu,
                                                 1024, 1, 1 << 30);

  // ===== layer 1 node transforms (fused; each x read once; part now dead) =====
  k_nodes<64, 16, false, __half><<<g(NU), blk, 0, stream>>>(
      x_user, W1_ub_s, a1_ub_s, W1_bu_d, a1_bu_d, hs_u1, as_u1, ad_u1, NU);
  k_nodes<64, 16, false, __half><<<g(NB), blk, 0, stream>>>(
      x_badge, W1_bu_s, a1_bu_s, W1_ub_d, a1_ub_d, hs_b1, as_b1, ad_b1, NB);

  // ===== layer 1 gathers =====
  for (int s = 0; s < NS_UB; ++s)
    k_gpart16<16><<<g(NB * 16), blk, 0, stream>>>(rp2_ub, col_ub, as_u1, ad_b1, hs_u1,
                                                  acc_ub, se_ub, NB, s, s == 0 ? 1 : 0);
  k_gfin<16><<<g(NB * 16), blk, 0, stream>>>(acc_ub, se_ub, b1_ub, hb, NB);
  k_gather16<16, __half><<<g(NU * 16), blk, 0, stream>>>(rp_bu, 1, col_bu, as_b1, ad_u1,
                                                         hs_b1, b1_bu, hu, NU);

  // ===== layer 2 node transforms (fused, relu folded) =====
  k_nodes<16, 2, true, float><<<g(NU), blk, 0, stream>>>(
      hu, W2_ub_s, a2_ub_s, W2_bu_d, a2_bu_d, hs2_ub, as2_ub, ad2_bu, NU);
  k_nodes<16, 2, true, float><<<g(NB), blk, 0, stream>>>(
      hb, W2_bu_s, a2_bu_s, W2_ub_d, a2_ub_d, hs2_bu, as2_bu, ad2_ub, NB);

  // ===== layer 2 gathers =====
  k_gather16<2, float><<<g(NB * 16), blk, 0, stream>>>(rp2_ub, NS_UB, col_ub, as2_ub,
                                                       ad2_ub, hs2_ub, b2_ub, ob, NB);
  k_gather16<2, float><<<g(NU * 16), blk, 0, stream>>>(rp_bu, 1, col_bu, as2_bu,
                                                       ad2_bu, hs2_bu, b2_bu, ou, NU);
}